// Round 13
// baseline (417.434 us; speedup 1.0000x reference)
//
#include <hip/hip_runtime.h>
#include <math.h>

constexpr int B_  = 32;
constexpr int N_  = 200000;
constexpr int XSZ = 256;
constexpr int PADS = 257;                   // SoA LDS row stride (floats)

// scatter binning config
constexpr int NQ = 4;                        // quarters (image groups)
constexpr int BQ = 8;                        // images per quarter
constexpr int NSLAB = 64;                    // 4-row slabs per image
constexpr int BINS_Q = BQ * NSLAB;           // 512 bins per quarter
constexpr int FILLB = 256;                   // fill blocks
constexpr int PPB = 782;                     // points per fill block (256*782 >= 200000)
constexpr size_t ENT_N = (size_t)N_ * BQ;    // 1.6M hard cap (each (n,b) pair <= 1 entry)

// workspace layout (bytes) — total ~30.8 MB (within proven 33.63 MB footprint)
constexpr size_t OFF_PART  = 0;                                   // 73728
constexpr size_t OFF_H     = 73728;                               // 1024
constexpr size_t OFF_R     = 74752;                               // 1152
constexpr size_t OFF_CNT   = 76800;                               // 256*512*4 = 524288
constexpr size_t OFF_TOT   = OFF_CNT + 524288;                    // 2048
constexpr size_t OFF_BB    = OFF_TOT + 2048;                      // 2048
constexpr size_t OFF_APR   = OFF_BB + 2048;                       // 4*512*256*4 = 2097152
constexpr size_t OFF_IMG   = OFF_APR + 2097152;                   // 8 MB
constexpr size_t OFF_ENT   = OFF_IMG + (size_t)B_ * XSZ * XSZ * 4;// posb 12.8 MB
constexpr size_t OFF_DELB  = OFF_ENT + ENT_N * 8;                 // 6.4 MB
constexpr size_t OFF_INTRA = OFF_DELB + ENT_N * 4;                // 524288 -> end ~30.8 MB
// post-scatter overlays (entries dead after last k_scatter2):
constexpr size_t OFF_TMP   = OFF_ENT;                             // 8 MB blur tmp
constexpr size_t OFF_FC    = OFF_ENT;                             // 16.8 MB float2 (after blur done)

__device__ __forceinline__ int rev8(int x) { return (int)(__brev((unsigned)x) >> 24); }

// shared projection: EXPLICIT fmaf so k_count and k_fill2 emit identical FP sequences
__device__ __forceinline__ void projPxPy(float c0, float c1, float c2,
                                         const float* sRb, const float* ssb,
                                         float& px, float& py) {
  px = fmaf(sRb[0], c0, fmaf(sRb[1], c1, fmaf(sRb[2], c2, ssb[0])));
  py = fmaf(sRb[3], c0, fmaf(sRb[4], c1, fmaf(sRb[5], c2, ssb[1])));
}

// ---------------- T reduction: T[j,i,k] = sum_n coords[n,j] * W1[3n+i,k] ----------------
__global__ __launch_bounds__(256) void k_reduceT(const float* __restrict__ coords,
                                                 const float* __restrict__ W1,
                                                 float* __restrict__ partial) {
  float acc[72];
  #pragma unroll
  for (int t = 0; t < 72; ++t) acc[t] = 0.f;
  int idx = blockIdx.x * 256 + threadIdx.x;
  for (int n = idx; n < N_; n += 256 * 256) {
    float c0 = coords[n * 3 + 0], c1 = coords[n * 3 + 1], c2 = coords[n * 3 + 2];
    const float4* w4 = reinterpret_cast<const float4*>(W1 + (size_t)n * 24);
    #pragma unroll
    for (int i = 0; i < 3; ++i) {
      float4 wa = w4[i * 2 + 0], wb = w4[i * 2 + 1];
      float wv[8] = {wa.x, wa.y, wa.z, wa.w, wb.x, wb.y, wb.z, wb.w};
      #pragma unroll
      for (int k = 0; k < 8; ++k) {
        acc[i * 8 + k]      += c0 * wv[k];
        acc[24 + i * 8 + k] += c1 * wv[k];
        acc[48 + i * 8 + k] += c2 * wv[k];
      }
    }
  }
  #pragma unroll
  for (int t = 0; t < 72; ++t) {
    float v = acc[t];
    for (int off = 32; off > 0; off >>= 1) v += __shfl_down(v, off, 64);
    acc[t] = v;
  }
  __shared__ float sred[4][72];
  int lane = threadIdx.x & 63, wv_ = threadIdx.x >> 6;
  if (lane == 0) {
    #pragma unroll
    for (int t = 0; t < 72; ++t) sred[wv_][t] = acc[t];
  }
  __syncthreads();
  if (threadIdx.x < 72) {
    int t = threadIdx.x;
    partial[blockIdx.x * 72 + t] = sred[0][t] + sred[1][t] + sred[2][t] + sred[3][t];
  }
}

// ---------------- per-batch: finalize T, rotation matrices, MLP head ----------------
__global__ __launch_bounds__(128) void k_batch(const float* __restrict__ partial,
                                               const float* __restrict__ rows,
                                               const float* __restrict__ b1,
                                               const float* __restrict__ Wh,
                                               const float* __restrict__ bh,
                                               float* __restrict__ hbuf,
                                               float* __restrict__ Rbuf) {
  __shared__ float T[72];
  int tid = threadIdx.x;
  if (tid < 72) {
    double s = 0.0;
    for (int i = 0; i < 256; ++i) s += (double)partial[i * 72 + tid];
    T[tid] = (float)s;
  }
  __syncthreads();
  if (tid < B_) {
    int b = tid;
    float al = rows[b * 3 + 0], be = rows[b * 3 + 1], ga = rows[b * 3 + 2];
    float sa, ca, sb, cb, sg, cg;
    sincosf(al, &sa, &ca); sincosf(be, &sb, &cb); sincosf(ga, &sg, &cg);
    float R[3][3];
    R[0][0] = ca * cb * cg - sa * sg; R[0][1] = -ca * cb * sg - sa * cg; R[0][2] = ca * sb;
    R[1][0] = sa * cb * cg + ca * sg; R[1][1] = -sa * cb * sg + ca * cg; R[1][2] = sa * sb;
    R[2][0] = -sb * cg;               R[2][1] = sb * sg;                 R[2][2] = cb;
    float h[8];
    #pragma unroll
    for (int k = 0; k < 8; ++k) {
      float z = b1[k];
      #pragma unroll
      for (int i = 0; i < 3; ++i)
        #pragma unroll
        for (int j = 0; j < 3; ++j)
          z += R[i][j] * T[(j * 3 + i) * 8 + k];
      h[k] = sinf(30.f * z);
    }
    for (int l = 0; l < 3; ++l) {
      float nh[8];
      #pragma unroll
      for (int k2 = 0; k2 < 8; ++k2) {
        float z = bh[l * 8 + k2];
        #pragma unroll
        for (int k1 = 0; k1 < 8; ++k1) z += h[k1] * Wh[l * 64 + k1 * 8 + k2];
        nh[k2] = sinf(z);
      }
      #pragma unroll
      for (int k = 0; k < 8; ++k) h[k] = nh[k];
    }
    #pragma unroll
    for (int k = 0; k < 8; ++k) hbuf[b * 8 + k] = h[k];
    #pragma unroll
    for (int i = 0; i < 3; ++i)
      #pragma unroll
      for (int j = 0; j < 3; ++j) Rbuf[b * 9 + i * 3 + j] = R[i][j];
  }
}

// ---------------- count: per (fill-block, bin) histogram ----------------
__global__ __launch_bounds__(512) void k_count(const float* __restrict__ coords,
                                               const float* __restrict__ Rbuf,
                                               const float* __restrict__ shifts,
                                               unsigned* __restrict__ cnt,
                                               int q) {
  __shared__ float sR[BQ][6];
  __shared__ float ss[BQ][2];
  __shared__ unsigned hist[BINS_Q];
  int tid = threadIdx.x;
  if (tid < BQ) {
    int b = q * BQ + tid;
    sR[tid][0] = Rbuf[b * 9 + 0] * 100.f; sR[tid][1] = Rbuf[b * 9 + 1] * 100.f; sR[tid][2] = Rbuf[b * 9 + 2] * 100.f;
    sR[tid][3] = Rbuf[b * 9 + 3] * 100.f; sR[tid][4] = Rbuf[b * 9 + 4] * 100.f; sR[tid][5] = Rbuf[b * 9 + 5] * 100.f;
    ss[tid][0] = 128.f - shifts[b * 2 + 0];
    ss[tid][1] = 128.f - shifts[b * 2 + 1];
  }
  hist[tid] = 0;
  __syncthreads();
  int pbase = blockIdx.x * PPB;
  #pragma unroll
  for (int k = 0; k < 2; ++k) {
    int off = tid + (k << 9);
    int n = pbase + off;
    if (off < PPB && n < N_) {
      float c0 = coords[n * 3], c1 = coords[n * 3 + 1], c2 = coords[n * 3 + 2];
      #pragma unroll
      for (int b = 0; b < BQ; ++b) {
        float px, py;
        projPxPy(c0, c1, c2, sR[b], ss[b], px, py);
        if (px >= -1.f && px < 256.f && py >= -1.f && py < 256.f) {
          int y0 = (int)floorf(py);
          int slab = (y0 < 0 ? 0 : y0) >> 2;
          atomicAdd(&hist[b * NSLAB + slab], 1u);
        }
      }
    }
  }
  __syncthreads();
  cnt[(size_t)blockIdx.x * BINS_Q + tid] = hist[tid];
}

// ---------------- offA: per-bin exclusive scan over 256 fill-blocks ----------------
__global__ __launch_bounds__(256) void k_offA(const unsigned* __restrict__ cnt,
                                              unsigned* __restrict__ intra,
                                              unsigned* __restrict__ totals) {
  int bin = blockIdx.x;
  int t = threadIdx.x;        // fill-block index
  unsigned orig = cnt[(size_t)t * BINS_Q + bin];
  unsigned v = orig;
  int lane = t & 63, wid = t >> 6;
  #pragma unroll
  for (int d = 1; d < 64; d <<= 1) { unsigned u = __shfl_up(v, d, 64); if (lane >= d) v += u; }
  __shared__ unsigned wsum[4];
  if (lane == 63) wsum[wid] = v;
  __syncthreads();
  unsigned woff = 0;
  #pragma unroll
  for (int w = 0; w < 4; ++w) if (w < wid) woff += wsum[w];
  intra[(size_t)t * BINS_Q + bin] = woff + v - orig;
  if (t == 255) totals[bin] = woff + v;
}

// ---------------- offB: exclusive scan of 512 bin totals ----------------
__global__ __launch_bounds__(512) void k_offB(const unsigned* __restrict__ totals,
                                              unsigned* __restrict__ binBase) {
  int t = threadIdx.x;
  unsigned orig = totals[t];
  unsigned v = orig;
  int lane = t & 63, wid = t >> 6;
  #pragma unroll
  for (int d = 1; d < 64; d <<= 1) { unsigned u = __shfl_up(v, d, 64); if (lane >= d) v += u; }
  __shared__ unsigned wsum[8];
  if (lane == 63) wsum[wid] = v;
  __syncthreads();
  unsigned woff = 0;
  #pragma unroll
  for (int w = 0; w < 8; ++w) if (w < wid) woff += wsum[w];
  binBase[t] = woff + v - orig;
}

// ---------------- fill2: write entries (px,py,delta) at exact bin-major offsets ----------------
__global__ __launch_bounds__(512) void k_fill2(const float* __restrict__ coords,
                                               const float* __restrict__ W5,
                                               const float* __restrict__ b5,
                                               const float* __restrict__ hbuf,
                                               const float* __restrict__ Rbuf,
                                               const float* __restrict__ shifts,
                                               const unsigned* __restrict__ cnt,
                                               const unsigned* __restrict__ intra,
                                               const unsigned* __restrict__ binBase,
                                               float2* __restrict__ posb,
                                               float* __restrict__ delb,
                                               int q) {
  __shared__ float sR[BQ][6];
  __shared__ float ss[BQ][2];
  __shared__ float sh[BQ][8];
  __shared__ unsigned scur[BINS_Q];
  __shared__ unsigned send[BINS_Q];
  int tid = threadIdx.x;
  if (tid < BQ) {
    int b = q * BQ + tid;
    sR[tid][0] = Rbuf[b * 9 + 0] * 100.f; sR[tid][1] = Rbuf[b * 9 + 1] * 100.f; sR[tid][2] = Rbuf[b * 9 + 2] * 100.f;
    sR[tid][3] = Rbuf[b * 9 + 3] * 100.f; sR[tid][4] = Rbuf[b * 9 + 4] * 100.f; sR[tid][5] = Rbuf[b * 9 + 5] * 100.f;
    ss[tid][0] = 128.f - shifts[b * 2 + 0];
    ss[tid][1] = 128.f - shifts[b * 2 + 1];
    #pragma unroll
    for (int k = 0; k < 8; ++k) sh[tid][k] = hbuf[b * 8 + k];
  }
  {
    unsigned st = binBase[tid] + intra[(size_t)blockIdx.x * BINS_Q + tid];
    scur[tid] = st;
    send[tid] = st + cnt[(size_t)blockIdx.x * BINS_Q + tid];
  }
  __syncthreads();
  int pbase = blockIdx.x * PPB;
  #pragma unroll
  for (int k = 0; k < 2; ++k) {
    int off = tid + (k << 9);
    int n = pbase + off;
    if (off < PPB && n < N_) {
      float c0 = coords[n * 3], c1 = coords[n * 3 + 1], c2 = coords[n * 3 + 2];
      float b5n = b5[n];
      float w5v[8];
      #pragma unroll
      for (int kk = 0; kk < 8; ++kk) w5v[kk] = W5[(size_t)kk * N_ + n];   // coalesced streams
      #pragma unroll
      for (int b = 0; b < BQ; ++b) {
        float px, py;
        projPxPy(c0, c1, c2, sR[b], ss[b], px, py);
        if (px >= -1.f && px < 256.f && py >= -1.f && py < 256.f) {
          int y0 = (int)floorf(py);
          int slab = (y0 < 0 ? 0 : y0) >> 2;
          int bin = b * NSLAB + slab;
          unsigned slot = atomicAdd(&scur[bin], 1u);
          if (slot < send[bin]) {            // safety net (should always hold)
            float delta = b5n;
            #pragma unroll
            for (int kk = 0; kk < 8; ++kk) delta = fmaf(sh[b][kk], w5v[kk], delta);
            posb[slot] = make_float2(px, py);
            delb[slot] = delta;
          }
        }
      }
    }
  }
}

// ---------------- scatter2: one block per bin, stream contiguous entries ----------------
__global__ __launch_bounds__(512) void k_scatter2(const float2* __restrict__ posb,
                                                  const float* __restrict__ delb,
                                                  const unsigned* __restrict__ binBase,
                                                  const unsigned* __restrict__ totals,
                                                  float* __restrict__ img,
                                                  float* __restrict__ apron,
                                                  int q) {
  __shared__ float tile[5 * XSZ];
  int tid = threadIdx.x;
  int bin = blockIdx.x;                 // [0, 512)
  int b_local = bin >> 6;
  int s = bin & 63;
  for (int i = tid; i < 5 * XSZ; i += 512) tile[i] = 0.f;
  __syncthreads();
  unsigned base = binBase[bin];
  unsigned cntv = totals[bin];
  int ybase = s << 2;
  for (unsigned i = tid; i < cntv; i += 512) {
    float2 pp = posb[base + i];
    float delta = delb[base + i];
    float x0f = floorf(pp.x), y0f = floorf(pp.y);
    float fx = pp.x - x0f, fy = pp.y - y0f;
    int x0 = (int)x0f;
    int r0 = (int)y0f - ybase;          // in [-1, 3]
    float wy0 = (1.f - fy) * delta, wy1 = fy * delta;
    bool xl = (x0 >= 0), xr = (x0 <= 254);
    if (r0 >= 0) {
      int c0i = r0 * XSZ + x0;
      if (xl) atomicAdd(&tile[c0i], (1.f - fx) * wy0);
      if (xr) atomicAdd(&tile[c0i + 1], fx * wy0);
    }
    int c1i = (r0 + 1) * XSZ + x0;
    if (xl) atomicAdd(&tile[c1i], (1.f - fx) * wy1);
    if (xr) atomicAdd(&tile[c1i + 1], fx * wy1);
  }
  __syncthreads();
  int b_global = q * BQ + b_local;
  float* imbase = img + (size_t)b_global * 65536 + (size_t)ybase * XSZ;
  for (int i = tid; i < 4 * XSZ; i += 512) imbase[i] = tile[i];
  if (tid < XSZ) apron[(size_t)(q * BINS_Q + bin) * XSZ + tid] = tile[4 * XSZ + tid];
}

// ---------------- apron fixup: add boundary rows ----------------
__global__ __launch_bounds__(256) void k_apron(const float* __restrict__ apron,
                                               float* __restrict__ img) {
  int bid = blockIdx.x;                 // b_global*64 + s
  int s = bid & 63;
  if (s == 63) return;                  // row 256 discarded
  int b = bid >> 6;
  int q = b >> 3, b_local = b & 7;
  int bin = b_local * NSLAB + s;
  int row = (s + 1) << 2;
  float* dst = img + (size_t)b * 65536 + (size_t)row * XSZ;
  dst[threadIdx.x] += apron[(size_t)(q * BINS_Q + bin) * XSZ + threadIdx.x];
}

// ---------------- separable Gaussian blur (zero-padded SAME) ----------------
__device__ __forceinline__ float bwv(int i) {
  const float bw[7] = {0.004433048f, 0.054005582f, 0.242036226f, 0.399050280f,
                       0.242036226f, 0.054005582f, 0.004433048f};
  return bw[i];
}

__global__ __launch_bounds__(256) void k_blurV(const float* __restrict__ in, float* __restrict__ out) {
  int i = blockIdx.x * 256 + threadIdx.x;
  int x = i & 255;
  int y = (i >> 8) & 255;
  const float* p = in + (i & ~65535);
  float s = 0.f;
  #pragma unroll
  for (int d = -3; d <= 3; ++d) {
    int yy = y + d;
    if ((unsigned)yy < XSZ) s += bwv(d + 3) * p[(yy << 8) + x];
  }
  out[i] = s;
}

__global__ __launch_bounds__(256) void k_blurH(const float* __restrict__ in, float* __restrict__ out) {
  int i = blockIdx.x * 256 + threadIdx.x;
  int x = i & 255;
  float s = 0.f;
  #pragma unroll
  for (int d = -3; d <= 3; ++d) {
    int xx = x + d;
    if ((unsigned)xx < XSZ) s += bwv(d + 3) * in[i + d];
  }
  out[i] = s;
}

// ---------------- FFT helpers: 256-pt, SoA in LDS, stride PADS ----------------
__device__ __forceinline__ void fft_dif_fwd(float* re, float* im, const float2* tw, int P, int tid) {
  for (int s = 7; s >= 0; --s) {
    __syncthreads();
    int half = 1 << s;
    for (int q = tid; q < (P << 7); q += 256) {
      int p = q >> 7, k = q & 127;
      int j = k & (half - 1);
      int i0 = ((k >> s) << (s + 1)) | j;
      int i1 = i0 + half;
      float* rp = re + p * PADS; float* ip = im + p * PADS;
      float ar = rp[i0], ai = ip[i0], br = rp[i1], bi = ip[i1];
      rp[i0] = ar + br; ip[i0] = ai + bi;
      float tr = ar - br, ti = ai - bi;
      float2 w = tw[j << (7 - s)];
      rp[i1] = tr * w.x - ti * w.y;
      ip[i1] = tr * w.y + ti * w.x;
    }
  }
  __syncthreads();
}

__device__ __forceinline__ void fft_dit_inv(float* re, float* im, const float2* tw, int P, int tid) {
  for (int s = 0; s <= 7; ++s) {
    __syncthreads();
    int half = 1 << s;
    for (int q = tid; q < (P << 7); q += 256) {
      int p = q >> 7, k = q & 127;
      int j = k & (half - 1);
      int i0 = ((k >> s) << (s + 1)) | j;
      int i1 = i0 + half;
      float* rp = re + p * PADS; float* ip = im + p * PADS;
      float2 w = tw[j << (7 - s)];               // conj -> (w.x, -w.y)
      float br = rp[i1], bi = ip[i1];
      float tr = br * w.x + bi * w.y;
      float ti = bi * w.x - br * w.y;
      float ar = rp[i0], ai = ip[i0];
      rp[i0] = ar + tr; ip[i0] = ai + ti;
      rp[i1] = ar - tr; ip[i1] = ai - ti;
    }
  }
  __syncthreads();
}

__device__ __forceinline__ void tw_init(float2* tw, int tid) {
  for (int k = tid; k < 128; k += 256) {
    float s_, c_;
    sincosf(-6.2831853071795864769f * (float)k / 256.0f, &s_, &c_);
    tw[k] = make_float2(c_, s_);
  }
}

// F1: row FFT (over x), DIF, store transposed: Fc[b][i][y] holds kx=rev8(i)
__global__ __launch_bounds__(256) void k_fft1(const float* __restrict__ img, float2* __restrict__ Fc) {
  __shared__ float re[16 * PADS], im[16 * PADS];
  __shared__ float2 tw[128];
  int tid = threadIdx.x;
  int b = blockIdx.x >> 4;
  int y0 = (blockIdx.x & 15) << 4;
  tw_init(tw, tid);
  const float* src = img + (size_t)b * 65536 + (size_t)y0 * 256;
  for (int q = tid; q < 4096; q += 256) {
    int j = q >> 8, x = q & 255;
    re[j * PADS + x] = src[j * 256 + x];
    im[j * PADS + x] = 0.f;
  }
  fft_dif_fwd(re, im, tw, 16, tid);
  float2* dst = Fc + (size_t)b * 65536;
  for (int q = tid; q < 4096; q += 256) {
    int j = q & 15, i = q >> 4;
    dst[(size_t)i * 256 + y0 + j] = make_float2(re[j * PADS + i], im[j * PADS + i]);
  }
}

// F2: column FFT (over y) DIF fwd, * ctf_ext, DIT inverse; in-place on Fc rows
__global__ __launch_bounds__(256) void k_fft2(float2* __restrict__ Fc, const float* __restrict__ ctf) {
  __shared__ float re[4 * PADS], im[4 * PADS];
  __shared__ float2 tw[128];
  int tid = threadIdx.x;
  int b = blockIdx.x >> 6;
  int r0 = (blockIdx.x & 63) << 2;
  tw_init(tw, tid);
  float2* base = Fc + (size_t)b * 65536 + (size_t)r0 * 256;
  for (int q = tid; q < 1024; q += 256) {
    int p = q >> 8, y = q & 255;
    float2 v = base[p * 256 + y];
    re[p * PADS + y] = v.x; im[p * PADS + y] = v.y;
  }
  fft_dif_fwd(re, im, tw, 4, tid);
  for (int q = tid; q < 1024; q += 256) {
    int p = q >> 8, iy = q & 255;
    int kx = rev8(r0 + p), ky = rev8(iy);
    float c;
    if (kx <= 128) c = ctf[((size_t)b * 256 + ky) * 129 + kx];
    else           c = ctf[((size_t)b * 256 + ((256 - ky) & 255)) * 129 + (256 - kx)];
    re[p * PADS + iy] *= c; im[p * PADS + iy] *= c;
  }
  fft_dit_inv(re, im, tw, 4, tid);
  for (int q = tid; q < 1024; q += 256) {
    int p = q >> 8, y = q & 255;
    base[p * 256 + y] = make_float2(re[p * PADS + y], im[p * PADS + y]);
  }
}

// F3: inverse row FFT (over kx). Rows of Fc are already bitrev-ordered in kx -> DIT direct.
__global__ __launch_bounds__(256) void k_fft3(const float2* __restrict__ Fc, float* __restrict__ out) {
  __shared__ float re[16 * PADS], im[16 * PADS];
  __shared__ float2 tw[128];
  int tid = threadIdx.x;
  int b = blockIdx.x >> 4;
  int y0 = (blockIdx.x & 15) << 4;
  tw_init(tw, tid);
  const float2* src = Fc + (size_t)b * 65536;
  for (int q = tid; q < 4096; q += 256) {
    int j = q & 15, r = q >> 4;
    float2 v = src[(size_t)r * 256 + y0 + j];
    re[j * PADS + r] = v.x; im[j * PADS + r] = v.y;
  }
  fft_dit_inv(re, im, tw, 16, tid);
  float* dst = out + (size_t)b * 65536 + (size_t)y0 * 256;
  for (int q = tid; q < 4096; q += 256) {
    int j = q >> 8, x = q & 255;
    dst[j * 256 + x] = re[j * PADS + x] * (1.f / 65536.f);
  }
}

extern "C" void kernel_launch(void* const* d_in, const int* in_sizes, int n_in,
                              void* d_out, int out_size, void* d_ws, size_t ws_size,
                              hipStream_t stream) {
  const float* rows   = (const float*)d_in[0];
  const float* shifts = (const float*)d_in[1];
  const float* coords = (const float*)d_in[2];
  const float* W1     = (const float*)d_in[3];
  const float* b1     = (const float*)d_in[4];
  const float* Wh     = (const float*)d_in[5];
  const float* bh     = (const float*)d_in[6];
  const float* W5     = (const float*)d_in[7];
  const float* b5     = (const float*)d_in[8];
  const float* ctf    = (const float*)d_in[9];
  float* out = (float*)d_out;
  char* ws = (char*)d_ws;

  float*    partial = (float*)(ws + OFF_PART);
  float*    hbuf    = (float*)(ws + OFF_H);
  float*    Rbuf    = (float*)(ws + OFF_R);
  unsigned* cnt     = (unsigned*)(ws + OFF_CNT);
  unsigned* totals  = (unsigned*)(ws + OFF_TOT);
  unsigned* binBase = (unsigned*)(ws + OFF_BB);
  unsigned* intra   = (unsigned*)(ws + OFF_INTRA);
  float*    apron   = (float*)(ws + OFF_APR);
  float*    img     = (float*)(ws + OFF_IMG);
  float2*   posb    = (float2*)(ws + OFF_ENT);
  float*    delb    = (float*)(ws + OFF_DELB);
  float*    tmp     = (float*)(ws + OFF_TMP);
  float2*   Fc      = (float2*)(ws + OFF_FC);

  k_reduceT<<<256, 256, 0, stream>>>(coords, W1, partial);
  k_batch<<<1, 128, 0, stream>>>(partial, rows, b1, Wh, bh, hbuf, Rbuf);
  for (int q = 0; q < NQ; ++q) {
    k_count<<<FILLB, 512, 0, stream>>>(coords, Rbuf, shifts, cnt, q);
    k_offA<<<BINS_Q, 256, 0, stream>>>(cnt, intra, totals);
    k_offB<<<1, 512, 0, stream>>>(totals, binBase);
    k_fill2<<<FILLB, 512, 0, stream>>>(coords, W5, b5, hbuf, Rbuf, shifts,
                                       cnt, intra, binBase, posb, delb, q);
    k_scatter2<<<BINS_Q, 512, 0, stream>>>(posb, delb, binBase, totals, img, apron, q);
  }
  k_apron<<<B_ * NSLAB, 256, 0, stream>>>(apron, img);
  k_blurV<<<B_ * XSZ * XSZ / 256, 256, 0, stream>>>(img, tmp);
  k_blurH<<<B_ * XSZ * XSZ / 256, 256, 0, stream>>>(tmp, img);
  k_fft1<<<B_ * 16, 256, 0, stream>>>(img, Fc);
  k_fft2<<<B_ * 64, 256, 0, stream>>>(Fc, ctf);
  k_fft3<<<B_ * 16, 256, 0, stream>>>(Fc, out);
}

// Round 15
// 214.646 us; speedup vs baseline: 1.9448x; 1.9448x over previous
//
#include <hip/hip_runtime.h>
#include <math.h>

constexpr int B_  = 32;
constexpr int N_  = 200000;
constexpr int XSZ = 256;
constexpr int PADS = 257;                   // SoA LDS row stride (floats)

// scatter binning config
constexpr int NQ = 4;                        // quarters (image groups)
constexpr int BQ = 8;                        // images per quarter
constexpr int NSLAB = 64;                    // 4-row slabs per image
constexpr int BINS_Q = BQ * NSLAB;           // 512 bins per quarter
constexpr int FILLB = 256;                   // fill blocks per quarter
constexpr int PPB = 782;                     // points per fill block (256*782 >= 200000)
constexpr unsigned ENT_N = 1600000;          // HARD upper bound: N_*BQ (each (n,b) pair <= 1 entry)

// fixed-point accumulation (native int LDS atomics)
constexpr float FP_SCALE = 4194304.f;        // 2^22
constexpr float FP_INV   = 1.f / 4194304.f;

// workspace layout (bytes) — total 32,924,672 (within proven 33,631,232 footprint)
constexpr size_t OFF_PART  = 0;                                   // 73728
constexpr size_t OFF_H     = 73728;                               // 1024
constexpr size_t OFF_R     = 74752;                               // 2048 pad
constexpr size_t OFF_CNT   = 76800;                               // u16: 4*256*512*2 = 1048576
constexpr size_t OFF_INTRA = OFF_CNT + 1048576;                   // u32: 2097152
constexpr size_t OFF_TOT   = OFF_INTRA + 2097152;                 // 8192
constexpr size_t OFF_BB    = OFF_TOT + 8192;                      // 8192
constexpr size_t OFF_APR   = OFF_BB + 8192;                       // 2097152
constexpr size_t OFF_IMG   = OFF_APR + 2097152;                   // 8388608
constexpr size_t OFF_ENT   = OFF_IMG + 8388608;                   // posb 12.8 MB
constexpr size_t OFF_DELB  = OFF_ENT + (size_t)ENT_N * 8;         // delb 6.4 MB -> end 32.9 MB
// post-scatter overlays (entries dead after last k_scatter2):
constexpr size_t OFF_TMP   = OFF_ENT;                             // 8 MB blur tmp
constexpr size_t OFF_FC    = OFF_ENT;                             // 16.8 MB float2 (after blur done)

__device__ __forceinline__ int rev8(int x) { return (int)(__brev((unsigned)x) >> 24); }

// shared projection: EXPLICIT fmaf so k_count and k_fill2 emit identical FP sequences
__device__ __forceinline__ void projPxPy(float c0, float c1, float c2,
                                         const float* sRb, const float* ssb,
                                         float& px, float& py) {
  px = fmaf(sRb[0], c0, fmaf(sRb[1], c1, fmaf(sRb[2], c2, ssb[0])));
  py = fmaf(sRb[3], c0, fmaf(sRb[4], c1, fmaf(sRb[5], c2, ssb[1])));
}

// ---------------- T reduction: T[j,i,k] = sum_n coords[n,j] * W1[3n+i,k] ----------------
__global__ __launch_bounds__(256) void k_reduceT(const float* __restrict__ coords,
                                                 const float* __restrict__ W1,
                                                 float* __restrict__ partial) {
  float acc[72];
  #pragma unroll
  for (int t = 0; t < 72; ++t) acc[t] = 0.f;
  int idx = blockIdx.x * 256 + threadIdx.x;
  for (int n = idx; n < N_; n += 256 * 256) {
    float c0 = coords[n * 3 + 0], c1 = coords[n * 3 + 1], c2 = coords[n * 3 + 2];
    const float4* w4 = reinterpret_cast<const float4*>(W1 + (size_t)n * 24);
    #pragma unroll
    for (int i = 0; i < 3; ++i) {
      float4 wa = w4[i * 2 + 0], wb = w4[i * 2 + 1];
      float wv[8] = {wa.x, wa.y, wa.z, wa.w, wb.x, wb.y, wb.z, wb.w};
      #pragma unroll
      for (int k = 0; k < 8; ++k) {
        acc[i * 8 + k]      += c0 * wv[k];
        acc[24 + i * 8 + k] += c1 * wv[k];
        acc[48 + i * 8 + k] += c2 * wv[k];
      }
    }
  }
  #pragma unroll
  for (int t = 0; t < 72; ++t) {
    float v = acc[t];
    for (int off = 32; off > 0; off >>= 1) v += __shfl_down(v, off, 64);
    acc[t] = v;
  }
  __shared__ float sred[4][72];
  int lane = threadIdx.x & 63, wv_ = threadIdx.x >> 6;
  if (lane == 0) {
    #pragma unroll
    for (int t = 0; t < 72; ++t) sred[wv_][t] = acc[t];
  }
  __syncthreads();
  if (threadIdx.x < 72) {
    int t = threadIdx.x;
    partial[blockIdx.x * 72 + t] = sred[0][t] + sred[1][t] + sred[2][t] + sred[3][t];
  }
}

// ---------------- per-batch: finalize T, rotation matrices, MLP head ----------------
__global__ __launch_bounds__(128) void k_batch(const float* __restrict__ partial,
                                               const float* __restrict__ rows,
                                               const float* __restrict__ b1,
                                               const float* __restrict__ Wh,
                                               const float* __restrict__ bh,
                                               float* __restrict__ hbuf,
                                               float* __restrict__ Rbuf) {
  __shared__ float T[72];
  int tid = threadIdx.x;
  if (tid < 72) {
    double s = 0.0;
    for (int i = 0; i < 256; ++i) s += (double)partial[i * 72 + tid];
    T[tid] = (float)s;
  }
  __syncthreads();
  if (tid < B_) {
    int b = tid;
    float al = rows[b * 3 + 0], be = rows[b * 3 + 1], ga = rows[b * 3 + 2];
    float sa, ca, sb, cb, sg, cg;
    sincosf(al, &sa, &ca); sincosf(be, &sb, &cb); sincosf(ga, &sg, &cg);
    float R[3][3];
    R[0][0] = ca * cb * cg - sa * sg; R[0][1] = -ca * cb * sg - sa * cg; R[0][2] = ca * sb;
    R[1][0] = sa * cb * cg + ca * sg; R[1][1] = -sa * cb * sg + ca * cg; R[1][2] = sa * sb;
    R[2][0] = -sb * cg;               R[2][1] = sb * sg;                 R[2][2] = cb;
    float h[8];
    #pragma unroll
    for (int k = 0; k < 8; ++k) {
      float z = b1[k];
      #pragma unroll
      for (int i = 0; i < 3; ++i)
        #pragma unroll
        for (int j = 0; j < 3; ++j)
          z += R[i][j] * T[(j * 3 + i) * 8 + k];
      h[k] = sinf(30.f * z);
    }
    for (int l = 0; l < 3; ++l) {
      float nh[8];
      #pragma unroll
      for (int k2 = 0; k2 < 8; ++k2) {
        float z = bh[l * 8 + k2];
        #pragma unroll
        for (int k1 = 0; k1 < 8; ++k1) z += h[k1] * Wh[l * 64 + k1 * 8 + k2];
        nh[k2] = sinf(z);
      }
      #pragma unroll
      for (int k = 0; k < 8; ++k) h[k] = nh[k];
    }
    #pragma unroll
    for (int k = 0; k < 8; ++k) hbuf[b * 8 + k] = h[k];
    #pragma unroll
    for (int i = 0; i < 3; ++i)
      #pragma unroll
      for (int j = 0; j < 3; ++j) Rbuf[b * 9 + i * 3 + j] = R[i][j];
  }
}

// ---------------- count: per (quarter, fill-block, bin) histogram — ALL quarters ----------------
__global__ __launch_bounds__(512) void k_count(const float* __restrict__ coords,
                                               const float* __restrict__ Rbuf,
                                               const float* __restrict__ shifts,
                                               unsigned short* __restrict__ cnt) {
  __shared__ float sR[BQ][6];
  __shared__ float ss[BQ][2];
  __shared__ unsigned hist[BINS_Q];
  int tid = threadIdx.x;
  int q = blockIdx.x >> 8;            // FILLB = 256
  int fb = blockIdx.x & 255;
  if (tid < BQ) {
    int b = q * BQ + tid;
    sR[tid][0] = Rbuf[b * 9 + 0] * 100.f; sR[tid][1] = Rbuf[b * 9 + 1] * 100.f; sR[tid][2] = Rbuf[b * 9 + 2] * 100.f;
    sR[tid][3] = Rbuf[b * 9 + 3] * 100.f; sR[tid][4] = Rbuf[b * 9 + 4] * 100.f; sR[tid][5] = Rbuf[b * 9 + 5] * 100.f;
    ss[tid][0] = 128.f - shifts[b * 2 + 0];
    ss[tid][1] = 128.f - shifts[b * 2 + 1];
  }
  hist[tid] = 0;
  __syncthreads();
  int pbase = fb * PPB;
  #pragma unroll
  for (int k = 0; k < 2; ++k) {
    int off = tid + (k << 9);
    int n = pbase + off;
    if (off < PPB && n < N_) {
      float c0 = coords[n * 3], c1 = coords[n * 3 + 1], c2 = coords[n * 3 + 2];
      #pragma unroll
      for (int b = 0; b < BQ; ++b) {
        float px, py;
        projPxPy(c0, c1, c2, sR[b], ss[b], px, py);
        if (px >= -1.f && px < 256.f && py >= -1.f && py < 256.f) {
          int y0 = (int)floorf(py);
          int slab = (y0 < 0 ? 0 : y0) >> 2;
          atomicAdd(&hist[b * NSLAB + slab], 1u);
        }
      }
    }
  }
  __syncthreads();
  cnt[(size_t)blockIdx.x * BINS_Q + tid] = (unsigned short)hist[tid];
}

// ---------------- offA: per-(quarter,bin) exclusive scan over 256 fill-blocks ----------------
__global__ __launch_bounds__(256) void k_offA(const unsigned short* __restrict__ cnt,
                                              unsigned* __restrict__ intra,
                                              unsigned* __restrict__ totals) {
  int q = blockIdx.x >> 9;            // BINS_Q = 512
  int bin = blockIdx.x & 511;
  int t = threadIdx.x;                // fill-block index
  size_t cbase = ((size_t)q * FILLB + t) * BINS_Q + bin;
  unsigned orig = cnt[cbase];
  unsigned v = orig;
  int lane = t & 63, wid = t >> 6;
  #pragma unroll
  for (int d = 1; d < 64; d <<= 1) { unsigned u = __shfl_up(v, d, 64); if (lane >= d) v += u; }
  __shared__ unsigned wsum[4];
  if (lane == 63) wsum[wid] = v;
  __syncthreads();
  unsigned woff = 0;
  #pragma unroll
  for (int w = 0; w < 4; ++w) if (w < wid) woff += wsum[w];
  intra[cbase] = woff + v - orig;
  if (t == 255) totals[q * BINS_Q + bin] = woff + v;
}

// ---------------- offB: per-quarter exclusive scan of 512 bin totals ----------------
__global__ __launch_bounds__(512) void k_offB(const unsigned* __restrict__ totals,
                                              unsigned* __restrict__ binBase) {
  int q = blockIdx.x;
  int t = threadIdx.x;
  unsigned orig = totals[q * BINS_Q + t];
  unsigned v = orig;
  int lane = t & 63, wid = t >> 6;
  #pragma unroll
  for (int d = 1; d < 64; d <<= 1) { unsigned u = __shfl_up(v, d, 64); if (lane >= d) v += u; }
  __shared__ unsigned wsum[8];
  if (lane == 63) wsum[wid] = v;
  __syncthreads();
  unsigned woff = 0;
  #pragma unroll
  for (int w = 0; w < 8; ++w) if (w < wid) woff += wsum[w];
  binBase[q * BINS_Q + t] = woff + v - orig;
}

// ---------------- fill2: write entries (px,py,delta) at exact bin-major offsets ----------------
__global__ __launch_bounds__(512) void k_fill2(const float* __restrict__ coords,
                                               const float* __restrict__ W5,
                                               const float* __restrict__ b5,
                                               const float* __restrict__ hbuf,
                                               const float* __restrict__ Rbuf,
                                               const float* __restrict__ shifts,
                                               const unsigned* __restrict__ intra,
                                               const unsigned* __restrict__ binBase,
                                               float2* __restrict__ posb,
                                               float* __restrict__ delb,
                                               int q) {
  __shared__ float sR[BQ][6];
  __shared__ float ss[BQ][2];
  __shared__ float sh[BQ][8];
  __shared__ unsigned scur[BINS_Q];
  int tid = threadIdx.x;
  if (tid < BQ) {
    int b = q * BQ + tid;
    sR[tid][0] = Rbuf[b * 9 + 0] * 100.f; sR[tid][1] = Rbuf[b * 9 + 1] * 100.f; sR[tid][2] = Rbuf[b * 9 + 2] * 100.f;
    sR[tid][3] = Rbuf[b * 9 + 3] * 100.f; sR[tid][4] = Rbuf[b * 9 + 4] * 100.f; sR[tid][5] = Rbuf[b * 9 + 5] * 100.f;
    ss[tid][0] = 128.f - shifts[b * 2 + 0];
    ss[tid][1] = 128.f - shifts[b * 2 + 1];
    #pragma unroll
    for (int k = 0; k < 8; ++k) sh[tid][k] = hbuf[b * 8 + k];
  }
  scur[tid] = binBase[q * BINS_Q + tid] + intra[((size_t)q * FILLB + blockIdx.x) * BINS_Q + tid];
  __syncthreads();
  int pbase = blockIdx.x * PPB;
  #pragma unroll
  for (int k = 0; k < 2; ++k) {
    int off = tid + (k << 9);
    int n = pbase + off;
    if (off < PPB && n < N_) {
      float c0 = coords[n * 3], c1 = coords[n * 3 + 1], c2 = coords[n * 3 + 2];
      float b5n = b5[n];
      float w5v[8];
      #pragma unroll
      for (int kk = 0; kk < 8; ++kk) w5v[kk] = W5[(size_t)kk * N_ + n];   // coalesced streams
      #pragma unroll
      for (int b = 0; b < BQ; ++b) {
        float px, py;
        projPxPy(c0, c1, c2, sR[b], ss[b], px, py);
        if (px >= -1.f && px < 256.f && py >= -1.f && py < 256.f) {
          int y0 = (int)floorf(py);
          int slab = (y0 < 0 ? 0 : y0) >> 2;
          int bin = b * NSLAB + slab;
          unsigned slot = atomicAdd(&scur[bin], 1u);
          if (slot < ENT_N) {                // paranoid OOB guard (exact counts => never hit)
            float delta = b5n;
            #pragma unroll
            for (int kk = 0; kk < 8; ++kk) delta = fmaf(sh[b][kk], w5v[kk], delta);
            posb[slot] = make_float2(px, py);
            delb[slot] = delta;
          }
        }
      }
    }
  }
}

// ---------------- scatter2: one block per bin, stream entries, INT LDS atomics ----------------
__global__ __launch_bounds__(512) void k_scatter2(const float2* __restrict__ posb,
                                                  const float* __restrict__ delb,
                                                  const unsigned* __restrict__ binBase,
                                                  const unsigned* __restrict__ totals,
                                                  float* __restrict__ img,
                                                  float* __restrict__ apron,
                                                  int q) {
  __shared__ int tile[5 * XSZ];
  int tid = threadIdx.x;
  int bin = blockIdx.x;                 // [0, 512)
  int b_local = bin >> 6;
  int s = bin & 63;
  for (int i = tid; i < 5 * XSZ; i += 512) tile[i] = 0;
  __syncthreads();
  unsigned base = binBase[q * BINS_Q + bin];
  unsigned cntv = totals[q * BINS_Q + bin];
  if (base >= ENT_N) cntv = 0;
  else if (base + cntv > ENT_N) cntv = ENT_N - base;
  int ybase = s << 2;
  for (unsigned i = tid; i < cntv; i += 512) {
    float2 pp = posb[base + i];
    float delta = delb[base + i];
    float x0f = floorf(pp.x), y0f = floorf(pp.y);
    float fx = pp.x - x0f, fy = pp.y - y0f;
    int x0 = (int)x0f;
    int r0 = (int)y0f - ybase;          // in [-1, 3]
    float wy0 = (1.f - fy) * delta * FP_SCALE;
    float wy1 = fy * delta * FP_SCALE;
    bool xl = (x0 >= 0), xr = (x0 <= 254);
    if (r0 >= 0) {
      int c0i = r0 * XSZ + x0;
      if (xl) atomicAdd(&tile[c0i], __float2int_rn((1.f - fx) * wy0));
      if (xr) atomicAdd(&tile[c0i + 1], __float2int_rn(fx * wy0));
    }
    int c1i = (r0 + 1) * XSZ + x0;
    if (xl) atomicAdd(&tile[c1i], __float2int_rn((1.f - fx) * wy1));
    if (xr) atomicAdd(&tile[c1i + 1], __float2int_rn(fx * wy1));
  }
  __syncthreads();
  int b_global = q * BQ + b_local;
  float* imbase = img + (size_t)b_global * 65536 + (size_t)ybase * XSZ;
  for (int i = tid; i < 4 * XSZ; i += 512) imbase[i] = (float)tile[i] * FP_INV;
  if (tid < XSZ) apron[(size_t)(q * BINS_Q + bin) * XSZ + tid] = (float)tile[4 * XSZ + tid] * FP_INV;
}

// ---------------- apron fixup: add boundary rows ----------------
__global__ __launch_bounds__(256) void k_apron(const float* __restrict__ apron,
                                               float* __restrict__ img) {
  int bid = blockIdx.x;                 // b_global*64 + s
  int s = bid & 63;
  if (s == 63) return;                  // row 256 discarded
  int b = bid >> 6;
  int q = b >> 3, b_local = b & 7;
  int bin = b_local * NSLAB + s;
  int row = (s + 1) << 2;
  float* dst = img + (size_t)b * 65536 + (size_t)row * XSZ;
  dst[threadIdx.x] += apron[(size_t)(q * BINS_Q + bin) * XSZ + threadIdx.x];
}

// ---------------- separable Gaussian blur (zero-padded SAME) ----------------
__device__ __forceinline__ float bwv(int i) {
  const float bw[7] = {0.004433048f, 0.054005582f, 0.242036226f, 0.399050280f,
                       0.242036226f, 0.054005582f, 0.004433048f};
  return bw[i];
}

__global__ __launch_bounds__(256) void k_blurV(const float* __restrict__ in, float* __restrict__ out) {
  int i = blockIdx.x * 256 + threadIdx.x;
  int x = i & 255;
  int y = (i >> 8) & 255;
  const float* p = in + (i & ~65535);
  float s = 0.f;
  #pragma unroll
  for (int d = -3; d <= 3; ++d) {
    int yy = y + d;
    if ((unsigned)yy < XSZ) s += bwv(d + 3) * p[(yy << 8) + x];
  }
  out[i] = s;
}

__global__ __launch_bounds__(256) void k_blurH(const float* __restrict__ in, float* __restrict__ out) {
  int i = blockIdx.x * 256 + threadIdx.x;
  int x = i & 255;
  float s = 0.f;
  #pragma unroll
  for (int d = -3; d <= 3; ++d) {
    int xx = x + d;
    if ((unsigned)xx < XSZ) s += bwv(d + 3) * in[i + d];
  }
  out[i] = s;
}

// ---------------- FFT helpers: 256-pt, SoA in LDS, stride PADS ----------------
__device__ __forceinline__ void fft_dif_fwd(float* re, float* im, const float2* tw, int P, int tid) {
  for (int s = 7; s >= 0; --s) {
    __syncthreads();
    int half = 1 << s;
    for (int q = tid; q < (P << 7); q += 256) {
      int p = q >> 7, k = q & 127;
      int j = k & (half - 1);
      int i0 = ((k >> s) << (s + 1)) | j;
      int i1 = i0 + half;
      float* rp = re + p * PADS; float* ip = im + p * PADS;
      float ar = rp[i0], ai = ip[i0], br = rp[i1], bi = ip[i1];
      rp[i0] = ar + br; ip[i0] = ai + bi;
      float tr = ar - br, ti = ai - bi;
      float2 w = tw[j << (7 - s)];
      rp[i1] = tr * w.x - ti * w.y;
      ip[i1] = tr * w.y + ti * w.x;
    }
  }
  __syncthreads();
}

__device__ __forceinline__ void fft_dit_inv(float* re, float* im, const float2* tw, int P, int tid) {
  for (int s = 0; s <= 7; ++s) {
    __syncthreads();
    int half = 1 << s;
    for (int q = tid; q < (P << 7); q += 256) {
      int p = q >> 7, k = q & 127;
      int j = k & (half - 1);
      int i0 = ((k >> s) << (s + 1)) | j;
      int i1 = i0 + half;
      float* rp = re + p * PADS; float* ip = im + p * PADS;
      float2 w = tw[j << (7 - s)];               // conj -> (w.x, -w.y)
      float br = rp[i1], bi = ip[i1];
      float tr = br * w.x + bi * w.y;
      float ti = bi * w.x - br * w.y;
      float ar = rp[i0], ai = ip[i0];
      rp[i0] = ar + tr; ip[i0] = ai + ti;
      rp[i1] = ar - tr; ip[i1] = ai - ti;
    }
  }
  __syncthreads();
}

__device__ __forceinline__ void tw_init(float2* tw, int tid) {
  for (int k = tid; k < 128; k += 256) {
    float s_, c_;
    sincosf(-6.2831853071795864769f * (float)k / 256.0f, &s_, &c_);
    tw[k] = make_float2(c_, s_);
  }
}

// F1: row FFT (over x), DIF, store transposed: Fc[b][i][y] holds kx=rev8(i)
__global__ __launch_bounds__(256) void k_fft1(const float* __restrict__ img, float2* __restrict__ Fc) {
  __shared__ float re[16 * PADS], im[16 * PADS];
  __shared__ float2 tw[128];
  int tid = threadIdx.x;
  int b = blockIdx.x >> 4;
  int y0 = (blockIdx.x & 15) << 4;
  tw_init(tw, tid);
  const float* src = img + (size_t)b * 65536 + (size_t)y0 * 256;
  for (int q = tid; q < 4096; q += 256) {
    int j = q >> 8, x = q & 255;
    re[j * PADS + x] = src[j * 256 + x];
    im[j * PADS + x] = 0.f;
  }
  fft_dif_fwd(re, im, tw, 16, tid);
  float2* dst = Fc + (size_t)b * 65536;
  for (int q = tid; q < 4096; q += 256) {
    int j = q & 15, i = q >> 4;
    dst[(size_t)i * 256 + y0 + j] = make_float2(re[j * PADS + i], im[j * PADS + i]);
  }
}

// F2: column FFT (over y) DIF fwd, * ctf_ext, DIT inverse; in-place on Fc rows
__global__ __launch_bounds__(256) void k_fft2(float2* __restrict__ Fc, const float* __restrict__ ctf) {
  __shared__ float re[4 * PADS], im[4 * PADS];
  __shared__ float2 tw[128];
  int tid = threadIdx.x;
  int b = blockIdx.x >> 6;
  int r0 = (blockIdx.x & 63) << 2;
  tw_init(tw, tid);
  float2* base = Fc + (size_t)b * 65536 + (size_t)r0 * 256;
  for (int q = tid; q < 1024; q += 256) {
    int p = q >> 8, y = q & 255;
    float2 v = base[p * 256 + y];
    re[p * PADS + y] = v.x; im[p * PADS + y] = v.y;
  }
  fft_dif_fwd(re, im, tw, 4, tid);
  for (int q = tid; q < 1024; q += 256) {
    int p = q >> 8, iy = q & 255;
    int kx = rev8(r0 + p), ky = rev8(iy);
    float c;
    if (kx <= 128) c = ctf[((size_t)b * 256 + ky) * 129 + kx];
    else           c = ctf[((size_t)b * 256 + ((256 - ky) & 255)) * 129 + (256 - kx)];
    re[p * PADS + iy] *= c; im[p * PADS + iy] *= c;
  }
  fft_dit_inv(re, im, tw, 4, tid);
  for (int q = tid; q < 1024; q += 256) {
    int p = q >> 8, y = q & 255;
    base[p * 256 + y] = make_float2(re[p * PADS + y], im[p * PADS + y]);
  }
}

// F3: inverse row FFT (over kx). Rows of Fc are already bitrev-ordered in kx -> DIT direct.
__global__ __launch_bounds__(256) void k_fft3(const float2* __restrict__ Fc, float* __restrict__ out) {
  __shared__ float re[16 * PADS], im[16 * PADS];
  __shared__ float2 tw[128];
  int tid = threadIdx.x;
  int b = blockIdx.x >> 4;
  int y0 = (blockIdx.x & 15) << 4;
  tw_init(tw, tid);
  const float2* src = Fc + (size_t)b * 65536;
  for (int q = tid; q < 4096; q += 256) {
    int j = q & 15, r = q >> 4;
    float2 v = src[(size_t)r * 256 + y0 + j];
    re[j * PADS + r] = v.x; im[j * PADS + r] = v.y;
  }
  fft_dit_inv(re, im, tw, 16, tid);
  float* dst = out + (size_t)b * 65536 + (size_t)y0 * 256;
  for (int q = tid; q < 4096; q += 256) {
    int j = q >> 8, x = q & 255;
    dst[j * 256 + x] = re[j * PADS + x] * (1.f / 65536.f);
  }
}

extern "C" void kernel_launch(void* const* d_in, const int* in_sizes, int n_in,
                              void* d_out, int out_size, void* d_ws, size_t ws_size,
                              hipStream_t stream) {
  const float* rows   = (const float*)d_in[0];
  const float* shifts = (const float*)d_in[1];
  const float* coords = (const float*)d_in[2];
  const float* W1     = (const float*)d_in[3];
  const float* b1     = (const float*)d_in[4];
  const float* Wh     = (const float*)d_in[5];
  const float* bh     = (const float*)d_in[6];
  const float* W5     = (const float*)d_in[7];
  const float* b5     = (const float*)d_in[8];
  const float* ctf    = (const float*)d_in[9];
  float* out = (float*)d_out;
  char* ws = (char*)d_ws;

  float*          partial = (float*)(ws + OFF_PART);
  float*          hbuf    = (float*)(ws + OFF_H);
  float*          Rbuf    = (float*)(ws + OFF_R);
  unsigned short* cnt     = (unsigned short*)(ws + OFF_CNT);
  unsigned*       intra   = (unsigned*)(ws + OFF_INTRA);
  unsigned*       totals  = (unsigned*)(ws + OFF_TOT);
  unsigned*       binBase = (unsigned*)(ws + OFF_BB);
  float*          apron   = (float*)(ws + OFF_APR);
  float*          img     = (float*)(ws + OFF_IMG);
  float2*         posb    = (float2*)(ws + OFF_ENT);
  float*          delb    = (float*)(ws + OFF_DELB);
  float*          tmp     = (float*)(ws + OFF_TMP);
  float2*         Fc      = (float2*)(ws + OFF_FC);

  k_reduceT<<<256, 256, 0, stream>>>(coords, W1, partial);
  k_batch<<<1, 128, 0, stream>>>(partial, rows, b1, Wh, bh, hbuf, Rbuf);
  k_count<<<NQ * FILLB, 512, 0, stream>>>(coords, Rbuf, shifts, cnt);
  k_offA<<<NQ * BINS_Q, 256, 0, stream>>>(cnt, intra, totals);
  k_offB<<<NQ, 512, 0, stream>>>(totals, binBase);
  for (int q = 0; q < NQ; ++q) {
    k_fill2<<<FILLB, 512, 0, stream>>>(coords, W5, b5, hbuf, Rbuf, shifts,
                                       intra, binBase, posb, delb, q);
    k_scatter2<<<BINS_Q, 512, 0, stream>>>(posb, delb, binBase, totals, img, apron, q);
  }
  k_apron<<<B_ * NSLAB, 256, 0, stream>>>(apron, img);
  k_blurV<<<B_ * XSZ * XSZ / 256, 256, 0, stream>>>(img, tmp);
  k_blurH<<<B_ * XSZ * XSZ / 256, 256, 0, stream>>>(tmp, img);
  k_fft1<<<B_ * 16, 256, 0, stream>>>(img, Fc);
  k_fft2<<<B_ * 64, 256, 0, stream>>>(Fc, ctf);
  k_fft3<<<B_ * 16, 256, 0, stream>>>(Fc, out);
}

// Round 18
// 206.605 us; speedup vs baseline: 2.0204x; 1.0389x over previous
//
#include <hip/hip_runtime.h>
#include <math.h>

constexpr int B_  = 32;
constexpr int N_  = 200000;
constexpr int XSZ = 256;
constexpr int PADS = 257;                   // SoA LDS row stride (floats)

// scatter binning config
constexpr int NQ = 4;                        // quarters (image groups)
constexpr int BQ = 8;                        // images per quarter
constexpr int NSLAB = 64;                    // 4-row slabs per image
constexpr int BINS_Q = BQ * NSLAB;           // 512 bins per quarter
constexpr int FILLB = 256;                   // fill blocks per quarter
constexpr int PPB = 782;                     // points per fill block (256*782 >= 200000)
constexpr unsigned ENT_N = 1600000;          // HARD upper bound per quarter: N_*BQ

// fixed-point accumulation (native int LDS atomics)
constexpr float FP_SCALE = 4194304.f;        // 2^22
constexpr float FP_INV   = 1.f / 4194304.f;

// workspace layout (bytes) — total ~90.5 MB (ws_size = 256 MiB per harness poison fills)
constexpr size_t OFF_PART  = 0;                                   // 73728
constexpr size_t OFF_H     = 73728;                               // 1024
constexpr size_t OFF_R     = 74752;                               // 2048 pad
constexpr size_t OFF_CNT   = 76800;                               // u16: 4*256*512*2 = 1048576
constexpr size_t OFF_INTRA = OFF_CNT + 1048576;                   // u32: 2097152
constexpr size_t OFF_TOT   = OFF_INTRA + 2097152;                 // 8192
constexpr size_t OFF_BB    = OFF_TOT + 8192;                      // 8192
constexpr size_t OFF_APR   = OFF_BB + 8192;                       // 2097152
constexpr size_t OFF_IMG   = OFF_APR + 2097152;                   // 8388608
constexpr size_t OFF_ENT   = OFF_IMG + 8388608;                   // posb: 4 quarters x 12.8 MB
constexpr size_t OFF_DELB  = OFF_ENT + (size_t)NQ * ENT_N * 8;    // delb: 4 quarters x 6.4 MB
// post-scatter overlays (entries dead after k_scatter2):
constexpr size_t OFF_TMP   = OFF_ENT;                             // 8 MB blur tmp
constexpr size_t OFF_FC    = OFF_ENT;                             // 16.8 MB float2 (after blur done)

__device__ __forceinline__ int rev8(int x) { return (int)(__brev((unsigned)x) >> 24); }

// shared projection: EXPLICIT fmaf so k_count and k_fill2 emit identical FP sequences
__device__ __forceinline__ void projPxPy(float c0, float c1, float c2,
                                         const float* sRb, const float* ssb,
                                         float& px, float& py) {
  px = fmaf(sRb[0], c0, fmaf(sRb[1], c1, fmaf(sRb[2], c2, ssb[0])));
  py = fmaf(sRb[3], c0, fmaf(sRb[4], c1, fmaf(sRb[5], c2, ssb[1])));
}

// ---------------- T reduction: T[j,i,k] = sum_n coords[n,j] * W1[3n+i,k] ----------------
__global__ __launch_bounds__(256) void k_reduceT(const float* __restrict__ coords,
                                                 const float* __restrict__ W1,
                                                 float* __restrict__ partial) {
  float acc[72];
  #pragma unroll
  for (int t = 0; t < 72; ++t) acc[t] = 0.f;
  int idx = blockIdx.x * 256 + threadIdx.x;
  for (int n = idx; n < N_; n += 256 * 256) {
    float c0 = coords[n * 3 + 0], c1 = coords[n * 3 + 1], c2 = coords[n * 3 + 2];
    const float4* w4 = reinterpret_cast<const float4*>(W1 + (size_t)n * 24);
    #pragma unroll
    for (int i = 0; i < 3; ++i) {
      float4 wa = w4[i * 2 + 0], wb = w4[i * 2 + 1];
      float wv[8] = {wa.x, wa.y, wa.z, wa.w, wb.x, wb.y, wb.z, wb.w};
      #pragma unroll
      for (int k = 0; k < 8; ++k) {
        acc[i * 8 + k]      += c0 * wv[k];
        acc[24 + i * 8 + k] += c1 * wv[k];
        acc[48 + i * 8 + k] += c2 * wv[k];
      }
    }
  }
  #pragma unroll
  for (int t = 0; t < 72; ++t) {
    float v = acc[t];
    for (int off = 32; off > 0; off >>= 1) v += __shfl_down(v, off, 64);
    acc[t] = v;
  }
  __shared__ float sred[4][72];
  int lane = threadIdx.x & 63, wv_ = threadIdx.x >> 6;
  if (lane == 0) {
    #pragma unroll
    for (int t = 0; t < 72; ++t) sred[wv_][t] = acc[t];
  }
  __syncthreads();
  if (threadIdx.x < 72) {
    int t = threadIdx.x;
    partial[blockIdx.x * 72 + t] = sred[0][t] + sred[1][t] + sred[2][t] + sred[3][t];
  }
}

// ---------------- per-batch: finalize T, rotation matrices, MLP head ----------------
__global__ __launch_bounds__(128) void k_batch(const float* __restrict__ partial,
                                               const float* __restrict__ rows,
                                               const float* __restrict__ b1,
                                               const float* __restrict__ Wh,
                                               const float* __restrict__ bh,
                                               float* __restrict__ hbuf,
                                               float* __restrict__ Rbuf) {
  __shared__ float T[72];
  int tid = threadIdx.x;
  if (tid < 72) {
    double s = 0.0;
    for (int i = 0; i < 256; ++i) s += (double)partial[i * 72 + tid];
    T[tid] = (float)s;
  }
  __syncthreads();
  if (tid < B_) {
    int b = tid;
    float al = rows[b * 3 + 0], be = rows[b * 3 + 1], ga = rows[b * 3 + 2];
    float sa, ca, sb, cb, sg, cg;
    sincosf(al, &sa, &ca); sincosf(be, &sb, &cb); sincosf(ga, &sg, &cg);
    float R[3][3];
    R[0][0] = ca * cb * cg - sa * sg; R[0][1] = -ca * cb * sg - sa * cg; R[0][2] = ca * sb;
    R[1][0] = sa * cb * cg + ca * sg; R[1][1] = -sa * cb * sg + ca * cg; R[1][2] = sa * sb;
    R[2][0] = -sb * cg;               R[2][1] = sb * sg;                 R[2][2] = cb;
    float h[8];
    #pragma unroll
    for (int k = 0; k < 8; ++k) {
      float z = b1[k];
      #pragma unroll
      for (int i = 0; i < 3; ++i)
        #pragma unroll
        for (int j = 0; j < 3; ++j)
          z += R[i][j] * T[(j * 3 + i) * 8 + k];
      h[k] = sinf(30.f * z);
    }
    for (int l = 0; l < 3; ++l) {
      float nh[8];
      #pragma unroll
      for (int k2 = 0; k2 < 8; ++k2) {
        float z = bh[l * 8 + k2];
        #pragma unroll
        for (int k1 = 0; k1 < 8; ++k1) z += h[k1] * Wh[l * 64 + k1 * 8 + k2];
        nh[k2] = sinf(z);
      }
      #pragma unroll
      for (int k = 0; k < 8; ++k) h[k] = nh[k];
    }
    #pragma unroll
    for (int k = 0; k < 8; ++k) hbuf[b * 8 + k] = h[k];
    #pragma unroll
    for (int i = 0; i < 3; ++i)
      #pragma unroll
      for (int j = 0; j < 3; ++j) Rbuf[b * 9 + i * 3 + j] = R[i][j];
  }
}

// ---------------- count: per (quarter, fill-block, bin) histogram — ALL quarters ----------------
__global__ __launch_bounds__(512) void k_count(const float* __restrict__ coords,
                                               const float* __restrict__ Rbuf,
                                               const float* __restrict__ shifts,
                                               unsigned short* __restrict__ cnt) {
  __shared__ float sR[BQ][6];
  __shared__ float ss[BQ][2];
  __shared__ unsigned hist[BINS_Q];
  int tid = threadIdx.x;
  int q = blockIdx.x >> 8;            // FILLB = 256
  int fb = blockIdx.x & 255;
  if (tid < BQ) {
    int b = q * BQ + tid;
    sR[tid][0] = Rbuf[b * 9 + 0] * 100.f; sR[tid][1] = Rbuf[b * 9 + 1] * 100.f; sR[tid][2] = Rbuf[b * 9 + 2] * 100.f;
    sR[tid][3] = Rbuf[b * 9 + 3] * 100.f; sR[tid][4] = Rbuf[b * 9 + 4] * 100.f; sR[tid][5] = Rbuf[b * 9 + 5] * 100.f;
    ss[tid][0] = 128.f - shifts[b * 2 + 0];
    ss[tid][1] = 128.f - shifts[b * 2 + 1];
  }
  hist[tid] = 0;
  __syncthreads();
  int pbase = fb * PPB;
  #pragma unroll
  for (int k = 0; k < 2; ++k) {
    int off = tid + (k << 9);
    int n = pbase + off;
    if (off < PPB && n < N_) {
      float c0 = coords[n * 3], c1 = coords[n * 3 + 1], c2 = coords[n * 3 + 2];
      #pragma unroll
      for (int b = 0; b < BQ; ++b) {
        float px, py;
        projPxPy(c0, c1, c2, sR[b], ss[b], px, py);
        if (px >= -1.f && px < 256.f && py >= -1.f && py < 256.f) {
          int y0 = (int)floorf(py);
          int slab = (y0 < 0 ? 0 : y0) >> 2;
          atomicAdd(&hist[b * NSLAB + slab], 1u);
        }
      }
    }
  }
  __syncthreads();
  cnt[(size_t)blockIdx.x * BINS_Q + tid] = (unsigned short)hist[tid];
}

// ---------------- offA: per-(quarter,bin) exclusive scan over 256 fill-blocks ----------------
__global__ __launch_bounds__(256) void k_offA(const unsigned short* __restrict__ cnt,
                                              unsigned* __restrict__ intra,
                                              unsigned* __restrict__ totals) {
  int q = blockIdx.x >> 9;            // BINS_Q = 512
  int bin = blockIdx.x & 511;
  int t = threadIdx.x;                // fill-block index
  size_t cbase = ((size_t)q * FILLB + t) * BINS_Q + bin;
  unsigned orig = cnt[cbase];
  unsigned v = orig;
  int lane = t & 63, wid = t >> 6;
  #pragma unroll
  for (int d = 1; d < 64; d <<= 1) { unsigned u = __shfl_up(v, d, 64); if (lane >= d) v += u; }
  __shared__ unsigned wsum[4];
  if (lane == 63) wsum[wid] = v;
  __syncthreads();
  unsigned woff = 0;
  #pragma unroll
  for (int w = 0; w < 4; ++w) if (w < wid) woff += wsum[w];
  intra[cbase] = woff + v - orig;
  if (t == 255) totals[q * BINS_Q + bin] = woff + v;
}

// ---------------- offB: per-quarter exclusive scan of 512 bin totals ----------------
__global__ __launch_bounds__(512) void k_offB(const unsigned* __restrict__ totals,
                                              unsigned* __restrict__ binBase) {
  int q = blockIdx.x;
  int t = threadIdx.x;
  unsigned orig = totals[q * BINS_Q + t];
  unsigned v = orig;
  int lane = t & 63, wid = t >> 6;
  #pragma unroll
  for (int d = 1; d < 64; d <<= 1) { unsigned u = __shfl_up(v, d, 64); if (lane >= d) v += u; }
  __shared__ unsigned wsum[8];
  if (lane == 63) wsum[wid] = v;
  __syncthreads();
  unsigned woff = 0;
  #pragma unroll
  for (int w = 0; w < 8; ++w) if (w < wid) woff += wsum[w];
  binBase[q * BINS_Q + t] = woff + v - orig;
}

// ---------------- fill2: ALL quarters; write entries at exact bin-major offsets ----------------
__global__ __launch_bounds__(512) void k_fill2(const float* __restrict__ coords,
                                               const float* __restrict__ W5,
                                               const float* __restrict__ b5,
                                               const float* __restrict__ hbuf,
                                               const float* __restrict__ Rbuf,
                                               const float* __restrict__ shifts,
                                               const unsigned* __restrict__ intra,
                                               const unsigned* __restrict__ binBase,
                                               float2* __restrict__ posb,
                                               float* __restrict__ delb) {
  __shared__ float sR[BQ][6];
  __shared__ float ss[BQ][2];
  __shared__ float sh[BQ][8];
  __shared__ unsigned scur[BINS_Q];
  int tid = threadIdx.x;
  int q = blockIdx.x >> 8;            // FILLB = 256
  int fb = blockIdx.x & 255;
  if (tid < BQ) {
    int b = q * BQ + tid;
    sR[tid][0] = Rbuf[b * 9 + 0] * 100.f; sR[tid][1] = Rbuf[b * 9 + 1] * 100.f; sR[tid][2] = Rbuf[b * 9 + 2] * 100.f;
    sR[tid][3] = Rbuf[b * 9 + 3] * 100.f; sR[tid][4] = Rbuf[b * 9 + 4] * 100.f; sR[tid][5] = Rbuf[b * 9 + 5] * 100.f;
    ss[tid][0] = 128.f - shifts[b * 2 + 0];
    ss[tid][1] = 128.f - shifts[b * 2 + 1];
    #pragma unroll
    for (int k = 0; k < 8; ++k) sh[tid][k] = hbuf[b * 8 + k];
  }
  scur[tid] = binBase[q * BINS_Q + tid] + intra[((size_t)q * FILLB + fb) * BINS_Q + tid];
  __syncthreads();
  float2* posq = posb + (size_t)q * ENT_N;
  float*  delq = delb + (size_t)q * ENT_N;
  int pbase = fb * PPB;
  #pragma unroll
  for (int k = 0; k < 2; ++k) {
    int off = tid + (k << 9);
    int n = pbase + off;
    if (off < PPB && n < N_) {
      float c0 = coords[n * 3], c1 = coords[n * 3 + 1], c2 = coords[n * 3 + 2];
      float b5n = b5[n];
      float w5v[8];
      #pragma unroll
      for (int kk = 0; kk < 8; ++kk) w5v[kk] = W5[(size_t)kk * N_ + n];   // coalesced streams
      #pragma unroll
      for (int b = 0; b < BQ; ++b) {
        float px, py;
        projPxPy(c0, c1, c2, sR[b], ss[b], px, py);
        if (px >= -1.f && px < 256.f && py >= -1.f && py < 256.f) {
          int y0 = (int)floorf(py);
          int slab = (y0 < 0 ? 0 : y0) >> 2;
          int bin = b * NSLAB + slab;
          unsigned slot = atomicAdd(&scur[bin], 1u);
          if (slot < ENT_N) {                // paranoid OOB guard (exact counts => never hit)
            float delta = b5n;
            #pragma unroll
            for (int kk = 0; kk < 8; ++kk) delta = fmaf(sh[b][kk], w5v[kk], delta);
            posq[slot] = make_float2(px, py);
            delq[slot] = delta;
          }
        }
      }
    }
  }
}

// ---------------- scatter2: ALL quarters; one block per (q,bin), INT LDS atomics ----------------
__global__ __launch_bounds__(512) void k_scatter2(const float2* __restrict__ posb,
                                                  const float* __restrict__ delb,
                                                  const unsigned* __restrict__ binBase,
                                                  const unsigned* __restrict__ totals,
                                                  float* __restrict__ img,
                                                  float* __restrict__ apron) {
  __shared__ int tile[5 * XSZ];
  int tid = threadIdx.x;
  int q = blockIdx.x >> 9;              // BINS_Q = 512
  int bin = blockIdx.x & 511;
  int b_local = bin >> 6;
  int s = bin & 63;
  for (int i = tid; i < 5 * XSZ; i += 512) tile[i] = 0;
  __syncthreads();
  unsigned base = binBase[q * BINS_Q + bin];
  unsigned cntv = totals[q * BINS_Q + bin];
  if (base >= ENT_N) cntv = 0;
  else if (base + cntv > ENT_N) cntv = ENT_N - base;
  const float2* posq = posb + (size_t)q * ENT_N;
  const float*  delq = delb + (size_t)q * ENT_N;
  int ybase = s << 2;
  for (unsigned i = tid; i < cntv; i += 512) {
    float2 pp = posq[base + i];
    float delta = delq[base + i];
    float x0f = floorf(pp.x), y0f = floorf(pp.y);
    float fx = pp.x - x0f, fy = pp.y - y0f;
    int x0 = (int)x0f;
    int r0 = (int)y0f - ybase;          // in [-1, 3]
    float wy0 = (1.f - fy) * delta * FP_SCALE;
    float wy1 = fy * delta * FP_SCALE;
    bool xl = (x0 >= 0), xr = (x0 <= 254);
    if (r0 >= 0) {
      int c0i = r0 * XSZ + x0;
      if (xl) atomicAdd(&tile[c0i], __float2int_rn((1.f - fx) * wy0));
      if (xr) atomicAdd(&tile[c0i + 1], __float2int_rn(fx * wy0));
    }
    int c1i = (r0 + 1) * XSZ + x0;
    if (xl) atomicAdd(&tile[c1i], __float2int_rn((1.f - fx) * wy1));
    if (xr) atomicAdd(&tile[c1i + 1], __float2int_rn(fx * wy1));
  }
  __syncthreads();
  int b_global = q * BQ + b_local;
  float* imbase = img + (size_t)b_global * 65536 + (size_t)ybase * XSZ;
  for (int i = tid; i < 4 * XSZ; i += 512) imbase[i] = (float)tile[i] * FP_INV;
  if (tid < XSZ) apron[(size_t)(q * BINS_Q + bin) * XSZ + tid] = (float)tile[4 * XSZ + tid] * FP_INV;
}

// ---------------- apron fixup: add boundary rows ----------------
__global__ __launch_bounds__(256) void k_apron(const float* __restrict__ apron,
                                               float* __restrict__ img) {
  int bid = blockIdx.x;                 // b_global*64 + s
  int s = bid & 63;
  if (s == 63) return;                  // row 256 discarded
  int b = bid >> 6;
  int q = b >> 3, b_local = b & 7;
  int bin = b_local * NSLAB + s;
  int row = (s + 1) << 2;
  float* dst = img + (size_t)b * 65536 + (size_t)row * XSZ;
  dst[threadIdx.x] += apron[(size_t)(q * BINS_Q + bin) * XSZ + threadIdx.x];
}

// ---------------- separable Gaussian blur (zero-padded SAME) ----------------
__device__ __forceinline__ float bwv(int i) {
  const float bw[7] = {0.004433048f, 0.054005582f, 0.242036226f, 0.399050280f,
                       0.242036226f, 0.054005582f, 0.004433048f};
  return bw[i];
}

__global__ __launch_bounds__(256) void k_blurV(const float* __restrict__ in, float* __restrict__ out) {
  int i = blockIdx.x * 256 + threadIdx.x;
  int x = i & 255;
  int y = (i >> 8) & 255;
  const float* p = in + (i & ~65535);
  float s = 0.f;
  #pragma unroll
  for (int d = -3; d <= 3; ++d) {
    int yy = y + d;
    if ((unsigned)yy < XSZ) s += bwv(d + 3) * p[(yy << 8) + x];
  }
  out[i] = s;
}

__global__ __launch_bounds__(256) void k_blurH(const float* __restrict__ in, float* __restrict__ out) {
  int i = blockIdx.x * 256 + threadIdx.x;
  int x = i & 255;
  float s = 0.f;
  #pragma unroll
  for (int d = -3; d <= 3; ++d) {
    int xx = x + d;
    if ((unsigned)xx < XSZ) s += bwv(d + 3) * in[i + d];
  }
  out[i] = s;
}

// ---------------- FFT helpers: 256-pt, SoA in LDS, stride PADS ----------------
__device__ __forceinline__ void fft_dif_fwd(float* re, float* im, const float2* tw, int P, int tid) {
  for (int s = 7; s >= 0; --s) {
    __syncthreads();
    int half = 1 << s;
    for (int q = tid; q < (P << 7); q += 256) {
      int p = q >> 7, k = q & 127;
      int j = k & (half - 1);
      int i0 = ((k >> s) << (s + 1)) | j;
      int i1 = i0 + half;
      float* rp = re + p * PADS; float* ip = im + p * PADS;
      float ar = rp[i0], ai = ip[i0], br = rp[i1], bi = ip[i1];
      rp[i0] = ar + br; ip[i0] = ai + bi;
      float tr = ar - br, ti = ai - bi;
      float2 w = tw[j << (7 - s)];
      rp[i1] = tr * w.x - ti * w.y;
      ip[i1] = tr * w.y + ti * w.x;
    }
  }
  __syncthreads();
}

__device__ __forceinline__ void fft_dit_inv(float* re, float* im, const float2* tw, int P, int tid) {
  for (int s = 0; s <= 7; ++s) {
    __syncthreads();
    int half = 1 << s;
    for (int q = tid; q < (P << 7); q += 256) {
      int p = q >> 7, k = q & 127;
      int j = k & (half - 1);
      int i0 = ((k >> s) << (s + 1)) | j;
      int i1 = i0 + half;
      float* rp = re + p * PADS; float* ip = im + p * PADS;
      float2 w = tw[j << (7 - s)];               // conj -> (w.x, -w.y)
      float br = rp[i1], bi = ip[i1];
      float tr = br * w.x + bi * w.y;
      float ti = bi * w.x - br * w.y;
      float ar = rp[i0], ai = ip[i0];
      rp[i0] = ar + tr; ip[i0] = ai + ti;
      rp[i1] = ar - tr; ip[i1] = ai - ti;
    }
  }
  __syncthreads();
}

__device__ __forceinline__ void tw_init(float2* tw, int tid) {
  for (int k = tid; k < 128; k += 256) {
    float s_, c_;
    sincosf(-6.2831853071795864769f * (float)k / 256.0f, &s_, &c_);
    tw[k] = make_float2(c_, s_);
  }
}

// F1: row FFT (over x), DIF, store transposed: Fc[b][i][y] holds kx=rev8(i)
__global__ __launch_bounds__(256) void k_fft1(const float* __restrict__ img, float2* __restrict__ Fc) {
  __shared__ float re[16 * PADS], im[16 * PADS];
  __shared__ float2 tw[128];
  int tid = threadIdx.x;
  int b = blockIdx.x >> 4;
  int y0 = (blockIdx.x & 15) << 4;
  tw_init(tw, tid);
  const float* src = img + (size_t)b * 65536 + (size_t)y0 * 256;
  for (int q = tid; q < 4096; q += 256) {
    int j = q >> 8, x = q & 255;
    re[j * PADS + x] = src[j * 256 + x];
    im[j * PADS + x] = 0.f;
  }
  fft_dif_fwd(re, im, tw, 16, tid);
  float2* dst = Fc + (size_t)b * 65536;
  for (int q = tid; q < 4096; q += 256) {
    int j = q & 15, i = q >> 4;
    dst[(size_t)i * 256 + y0 + j] = make_float2(re[j * PADS + i], im[j * PADS + i]);
  }
}

// F2: column FFT (over y) DIF fwd, * ctf_ext, DIT inverse; in-place on Fc rows
__global__ __launch_bounds__(256) void k_fft2(float2* __restrict__ Fc, const float* __restrict__ ctf) {
  __shared__ float re[4 * PADS], im[4 * PADS];
  __shared__ float2 tw[128];
  int tid = threadIdx.x;
  int b = blockIdx.x >> 6;
  int r0 = (blockIdx.x & 63) << 2;
  tw_init(tw, tid);
  float2* base = Fc + (size_t)b * 65536 + (size_t)r0 * 256;
  for (int q = tid; q < 1024; q += 256) {
    int p = q >> 8, y = q & 255;
    float2 v = base[p * 256 + y];
    re[p * PADS + y] = v.x; im[p * PADS + y] = v.y;
  }
  fft_dif_fwd(re, im, tw, 4, tid);
  for (int q = tid; q < 1024; q += 256) {
    int p = q >> 8, iy = q & 255;
    int kx = rev8(r0 + p), ky = rev8(iy);
    float c;
    if (kx <= 128) c = ctf[((size_t)b * 256 + ky) * 129 + kx];
    else           c = ctf[((size_t)b * 256 + ((256 - ky) & 255)) * 129 + (256 - kx)];
    re[p * PADS + iy] *= c; im[p * PADS + iy] *= c;
  }
  fft_dit_inv(re, im, tw, 4, tid);
  for (int q = tid; q < 1024; q += 256) {
    int p = q >> 8, y = q & 255;
    base[p * 256 + y] = make_float2(re[p * PADS + y], im[p * PADS + y]);
  }
}

// F3: inverse row FFT (over kx). Rows of Fc are already bitrev-ordered in kx -> DIT direct.
__global__ __launch_bounds__(256) void k_fft3(const float2* __restrict__ Fc, float* __restrict__ out) {
  __shared__ float re[16 * PADS], im[16 * PADS];
  __shared__ float2 tw[128];
  int tid = threadIdx.x;
  int b = blockIdx.x >> 4;
  int y0 = (blockIdx.x & 15) << 4;
  tw_init(tw, tid);
  const float2* src = Fc + (size_t)b * 65536;
  for (int q = tid; q < 4096; q += 256) {
    int j = q & 15, r = q >> 4;
    float2 v = src[(size_t)r * 256 + y0 + j];
    re[j * PADS + r] = v.x; im[j * PADS + r] = v.y;
  }
  fft_dit_inv(re, im, tw, 16, tid);
  float* dst = out + (size_t)b * 65536 + (size_t)y0 * 256;
  for (int q = tid; q < 4096; q += 256) {
    int j = q >> 8, x = q & 255;
    dst[j * 256 + x] = re[j * PADS + x] * (1.f / 65536.f);
  }
}

extern "C" void kernel_launch(void* const* d_in, const int* in_sizes, int n_in,
                              void* d_out, int out_size, void* d_ws, size_t ws_size,
                              hipStream_t stream) {
  const float* rows   = (const float*)d_in[0];
  const float* shifts = (const float*)d_in[1];
  const float* coords = (const float*)d_in[2];
  const float* W1     = (const float*)d_in[3];
  const float* b1     = (const float*)d_in[4];
  const float* Wh     = (const float*)d_in[5];
  const float* bh     = (const float*)d_in[6];
  const float* W5     = (const float*)d_in[7];
  const float* b5     = (const float*)d_in[8];
  const float* ctf    = (const float*)d_in[9];
  float* out = (float*)d_out;
  char* ws = (char*)d_ws;

  float*          partial = (float*)(ws + OFF_PART);
  float*          hbuf    = (float*)(ws + OFF_H);
  float*          Rbuf    = (float*)(ws + OFF_R);
  unsigned short* cnt     = (unsigned short*)(ws + OFF_CNT);
  unsigned*       intra   = (unsigned*)(ws + OFF_INTRA);
  unsigned*       totals  = (unsigned*)(ws + OFF_TOT);
  unsigned*       binBase = (unsigned*)(ws + OFF_BB);
  float*          apron   = (float*)(ws + OFF_APR);
  float*          img     = (float*)(ws + OFF_IMG);
  float2*         posb    = (float2*)(ws + OFF_ENT);
  float*          delb    = (float*)(ws + OFF_DELB);
  float*          tmp     = (float*)(ws + OFF_TMP);
  float2*         Fc      = (float2*)(ws + OFF_FC);

  k_reduceT<<<256, 256, 0, stream>>>(coords, W1, partial);
  k_batch<<<1, 128, 0, stream>>>(partial, rows, b1, Wh, bh, hbuf, Rbuf);
  k_count<<<NQ * FILLB, 512, 0, stream>>>(coords, Rbuf, shifts, cnt);
  k_offA<<<NQ * BINS_Q, 256, 0, stream>>>(cnt, intra, totals);
  k_offB<<<NQ, 512, 0, stream>>>(totals, binBase);
  k_fill2<<<NQ * FILLB, 512, 0, stream>>>(coords, W5, b5, hbuf, Rbuf, shifts,
                                          intra, binBase, posb, delb);
  k_scatter2<<<NQ * BINS_Q, 512, 0, stream>>>(posb, delb, binBase, totals, img, apron);
  k_apron<<<B_ * NSLAB, 256, 0, stream>>>(apron, img);
  k_blurV<<<B_ * XSZ * XSZ / 256, 256, 0, stream>>>(img, tmp);
  k_blurH<<<B_ * XSZ * XSZ / 256, 256, 0, stream>>>(tmp, img);
  k_fft1<<<B_ * 16, 256, 0, stream>>>(img, Fc);
  k_fft2<<<B_ * 64, 256, 0, stream>>>(Fc, ctf);
  k_fft3<<<B_ * 16, 256, 0, stream>>>(Fc, out);
}

// Round 19
// 179.577 us; speedup vs baseline: 2.3245x; 1.1505x over previous
//
#include <hip/hip_runtime.h>
#include <math.h>

constexpr int B_  = 32;
constexpr int N_  = 200000;
constexpr int XSZ = 256;
constexpr int PADS = 257;                   // SoA LDS row stride (floats)

// scatter binning config
constexpr int NQ = 4;                        // quarters (image groups)
constexpr int BQ = 8;                        // images per quarter
constexpr int NSLAB = 32;                    // 8-row slabs per image
constexpr int BINS_Q = BQ * NSLAB;           // 256 bins per quarter
constexpr int FILLB = 256;                   // fill blocks per quarter
constexpr int PPB = 782;                     // points per fill block (256*782 >= 200000)
constexpr unsigned ENT_N = 1600000;          // HARD upper bound per quarter: N_*BQ

// fixed-point accumulation (native int LDS atomics)
constexpr float FP_SCALE = 4194304.f;        // 2^22
constexpr float FP_INV   = 1.f / 4194304.f;

// workspace layout (bytes) — total ~65 MB (ws_size = 256 MiB per harness poison fills)
constexpr size_t OFF_PART  = 0;                                   // 73728
constexpr size_t OFF_H     = 73728;                               // 1024
constexpr size_t OFF_R     = 74752;                               // 2048 pad
constexpr size_t OFF_CNT   = 76800;                               // u16: 4*256*256*2 = 524288
constexpr size_t OFF_INTRA = OFF_CNT + 524288;                    // u32: 1048576
constexpr size_t OFF_TOT   = OFF_INTRA + 1048576;                 // 4096
constexpr size_t OFF_BB    = OFF_TOT + 4096;                      // 4096
constexpr size_t OFF_APR   = OFF_BB + 4096;                       // 4*256*256*4 = 1048576
constexpr size_t OFF_IMG   = OFF_APR + 1048576;                   // 8388608
constexpr size_t OFF_ENT   = OFF_IMG + 8388608;                   // entries: 4 quarters x 12.8 MB
// post-scatter overlays (entries dead after k_scatter2):
constexpr size_t OFF_TMP   = OFF_ENT;                             // 8 MB blur tmp
constexpr size_t OFF_FC    = OFF_ENT;                             // 16.8 MB float2 (after blur done)

__device__ __forceinline__ int rev8(int x) { return (int)(__brev((unsigned)x) >> 24); }

// shared projection: EXPLICIT fmaf so k_count, k_fill2, k_scatter2 emit identical FP sequences
__device__ __forceinline__ void projPxPy(float c0, float c1, float c2,
                                         const float* sRb, const float* ssb,
                                         float& px, float& py) {
  px = fmaf(sRb[0], c0, fmaf(sRb[1], c1, fmaf(sRb[2], c2, ssb[0])));
  py = fmaf(sRb[3], c0, fmaf(sRb[4], c1, fmaf(sRb[5], c2, ssb[1])));
}

// ---------------- T reduction: T[j,i,k] = sum_n coords[n,j] * W1[3n+i,k] ----------------
__global__ __launch_bounds__(256) void k_reduceT(const float* __restrict__ coords,
                                                 const float* __restrict__ W1,
                                                 float* __restrict__ partial) {
  float acc[72];
  #pragma unroll
  for (int t = 0; t < 72; ++t) acc[t] = 0.f;
  int idx = blockIdx.x * 256 + threadIdx.x;
  for (int n = idx; n < N_; n += 256 * 256) {
    float c0 = coords[n * 3 + 0], c1 = coords[n * 3 + 1], c2 = coords[n * 3 + 2];
    const float4* w4 = reinterpret_cast<const float4*>(W1 + (size_t)n * 24);
    #pragma unroll
    for (int i = 0; i < 3; ++i) {
      float4 wa = w4[i * 2 + 0], wb = w4[i * 2 + 1];
      float wv[8] = {wa.x, wa.y, wa.z, wa.w, wb.x, wb.y, wb.z, wb.w};
      #pragma unroll
      for (int k = 0; k < 8; ++k) {
        acc[i * 8 + k]      += c0 * wv[k];
        acc[24 + i * 8 + k] += c1 * wv[k];
        acc[48 + i * 8 + k] += c2 * wv[k];
      }
    }
  }
  #pragma unroll
  for (int t = 0; t < 72; ++t) {
    float v = acc[t];
    for (int off = 32; off > 0; off >>= 1) v += __shfl_down(v, off, 64);
    acc[t] = v;
  }
  __shared__ float sred[4][72];
  int lane = threadIdx.x & 63, wv_ = threadIdx.x >> 6;
  if (lane == 0) {
    #pragma unroll
    for (int t = 0; t < 72; ++t) sred[wv_][t] = acc[t];
  }
  __syncthreads();
  if (threadIdx.x < 72) {
    int t = threadIdx.x;
    partial[blockIdx.x * 72 + t] = sred[0][t] + sred[1][t] + sred[2][t] + sred[3][t];
  }
}

// ---------------- per-batch: finalize T, rotation matrices, MLP head ----------------
__global__ __launch_bounds__(128) void k_batch(const float* __restrict__ partial,
                                               const float* __restrict__ rows,
                                               const float* __restrict__ b1,
                                               const float* __restrict__ Wh,
                                               const float* __restrict__ bh,
                                               float* __restrict__ hbuf,
                                               float* __restrict__ Rbuf) {
  __shared__ float T[72];
  int tid = threadIdx.x;
  if (tid < 72) {
    double s = 0.0;
    for (int i = 0; i < 256; ++i) s += (double)partial[i * 72 + tid];
    T[tid] = (float)s;
  }
  __syncthreads();
  if (tid < B_) {
    int b = tid;
    float al = rows[b * 3 + 0], be = rows[b * 3 + 1], ga = rows[b * 3 + 2];
    float sa, ca, sb, cb, sg, cg;
    sincosf(al, &sa, &ca); sincosf(be, &sb, &cb); sincosf(ga, &sg, &cg);
    float R[3][3];
    R[0][0] = ca * cb * cg - sa * sg; R[0][1] = -ca * cb * sg - sa * cg; R[0][2] = ca * sb;
    R[1][0] = sa * cb * cg + ca * sg; R[1][1] = -sa * cb * sg + ca * cg; R[1][2] = sa * sb;
    R[2][0] = -sb * cg;               R[2][1] = sb * sg;                 R[2][2] = cb;
    float h[8];
    #pragma unroll
    for (int k = 0; k < 8; ++k) {
      float z = b1[k];
      #pragma unroll
      for (int i = 0; i < 3; ++i)
        #pragma unroll
        for (int j = 0; j < 3; ++j)
          z += R[i][j] * T[(j * 3 + i) * 8 + k];
      h[k] = sinf(30.f * z);
    }
    for (int l = 0; l < 3; ++l) {
      float nh[8];
      #pragma unroll
      for (int k2 = 0; k2 < 8; ++k2) {
        float z = bh[l * 8 + k2];
        #pragma unroll
        for (int k1 = 0; k1 < 8; ++k1) z += h[k1] * Wh[l * 64 + k1 * 8 + k2];
        nh[k2] = sinf(z);
      }
      #pragma unroll
      for (int k = 0; k < 8; ++k) h[k] = nh[k];
    }
    #pragma unroll
    for (int k = 0; k < 8; ++k) hbuf[b * 8 + k] = h[k];
    #pragma unroll
    for (int i = 0; i < 3; ++i)
      #pragma unroll
      for (int j = 0; j < 3; ++j) Rbuf[b * 9 + i * 3 + j] = R[i][j];
  }
}

// ---------------- count: per (quarter, fill-block, bin) histogram — ALL quarters ----------------
__global__ __launch_bounds__(512) void k_count(const float* __restrict__ coords,
                                               const float* __restrict__ Rbuf,
                                               const float* __restrict__ shifts,
                                               unsigned short* __restrict__ cnt) {
  __shared__ float sR[BQ][6];
  __shared__ float ss[BQ][2];
  __shared__ unsigned hist[BINS_Q];
  int tid = threadIdx.x;
  int q = blockIdx.x >> 8;            // FILLB = 256
  int fb = blockIdx.x & 255;
  if (tid < BQ) {
    int b = q * BQ + tid;
    sR[tid][0] = Rbuf[b * 9 + 0] * 100.f; sR[tid][1] = Rbuf[b * 9 + 1] * 100.f; sR[tid][2] = Rbuf[b * 9 + 2] * 100.f;
    sR[tid][3] = Rbuf[b * 9 + 3] * 100.f; sR[tid][4] = Rbuf[b * 9 + 4] * 100.f; sR[tid][5] = Rbuf[b * 9 + 5] * 100.f;
    ss[tid][0] = 128.f - shifts[b * 2 + 0];
    ss[tid][1] = 128.f - shifts[b * 2 + 1];
  }
  if (tid < BINS_Q) hist[tid] = 0;
  __syncthreads();
  int pbase = fb * PPB;
  #pragma unroll
  for (int k = 0; k < 2; ++k) {
    int off = tid + (k << 9);
    int n = pbase + off;
    if (off < PPB && n < N_) {
      float c0 = coords[n * 3], c1 = coords[n * 3 + 1], c2 = coords[n * 3 + 2];
      #pragma unroll
      for (int b = 0; b < BQ; ++b) {
        float px, py;
        projPxPy(c0, c1, c2, sR[b], ss[b], px, py);
        if (px >= -1.f && px < 256.f && py >= -1.f && py < 256.f) {
          int y0 = (int)floorf(py);
          int slab = (y0 < 0 ? 0 : y0) >> 3;
          atomicAdd(&hist[b * NSLAB + slab], 1u);
        }
      }
    }
  }
  __syncthreads();
  if (tid < BINS_Q) cnt[(size_t)blockIdx.x * BINS_Q + tid] = (unsigned short)hist[tid];
}

// ---------------- offA: per-(quarter,bin) exclusive scan over 256 fill-blocks ----------------
__global__ __launch_bounds__(256) void k_offA(const unsigned short* __restrict__ cnt,
                                              unsigned* __restrict__ intra,
                                              unsigned* __restrict__ totals) {
  int q = blockIdx.x >> 8;            // BINS_Q = 256
  int bin = blockIdx.x & 255;
  int t = threadIdx.x;                // fill-block index
  size_t cbase = ((size_t)q * FILLB + t) * BINS_Q + bin;
  unsigned orig = cnt[cbase];
  unsigned v = orig;
  int lane = t & 63, wid = t >> 6;
  #pragma unroll
  for (int d = 1; d < 64; d <<= 1) { unsigned u = __shfl_up(v, d, 64); if (lane >= d) v += u; }
  __shared__ unsigned wsum[4];
  if (lane == 63) wsum[wid] = v;
  __syncthreads();
  unsigned woff = 0;
  #pragma unroll
  for (int w = 0; w < 4; ++w) if (w < wid) woff += wsum[w];
  intra[cbase] = woff + v - orig;
  if (t == 255) totals[q * BINS_Q + bin] = woff + v;
}

// ---------------- offB: per-quarter exclusive scan of 256 bin totals ----------------
__global__ __launch_bounds__(256) void k_offB(const unsigned* __restrict__ totals,
                                              unsigned* __restrict__ binBase) {
  int q = blockIdx.x;
  int t = threadIdx.x;
  unsigned orig = totals[q * BINS_Q + t];
  unsigned v = orig;
  int lane = t & 63, wid = t >> 6;
  #pragma unroll
  for (int d = 1; d < 64; d <<= 1) { unsigned u = __shfl_up(v, d, 64); if (lane >= d) v += u; }
  __shared__ unsigned wsum[4];
  if (lane == 63) wsum[wid] = v;
  __syncthreads();
  unsigned woff = 0;
  #pragma unroll
  for (int w = 0; w < 4; ++w) if (w < wid) woff += wsum[w];
  binBase[q * BINS_Q + t] = woff + v - orig;
}

// ---------------- fill2: ALL quarters; entries = float2{n_bits, delta}, 8B single store ----------------
__global__ __launch_bounds__(512) void k_fill2(const float* __restrict__ coords,
                                               const float* __restrict__ W5,
                                               const float* __restrict__ b5,
                                               const float* __restrict__ hbuf,
                                               const float* __restrict__ Rbuf,
                                               const float* __restrict__ shifts,
                                               const unsigned* __restrict__ intra,
                                               const unsigned* __restrict__ binBase,
                                               float2* __restrict__ ent) {
  __shared__ float sR[BQ][6];
  __shared__ float ss[BQ][2];
  __shared__ float sh[BQ][8];
  __shared__ unsigned scur[BINS_Q];
  int tid = threadIdx.x;
  int q = blockIdx.x >> 8;            // FILLB = 256
  int fb = blockIdx.x & 255;
  if (tid < BQ) {
    int b = q * BQ + tid;
    sR[tid][0] = Rbuf[b * 9 + 0] * 100.f; sR[tid][1] = Rbuf[b * 9 + 1] * 100.f; sR[tid][2] = Rbuf[b * 9 + 2] * 100.f;
    sR[tid][3] = Rbuf[b * 9 + 3] * 100.f; sR[tid][4] = Rbuf[b * 9 + 4] * 100.f; sR[tid][5] = Rbuf[b * 9 + 5] * 100.f;
    ss[tid][0] = 128.f - shifts[b * 2 + 0];
    ss[tid][1] = 128.f - shifts[b * 2 + 1];
    #pragma unroll
    for (int k = 0; k < 8; ++k) sh[tid][k] = hbuf[b * 8 + k];
  }
  if (tid < BINS_Q)
    scur[tid] = binBase[q * BINS_Q + tid] + intra[((size_t)q * FILLB + fb) * BINS_Q + tid];
  __syncthreads();
  float2* entq = ent + (size_t)q * ENT_N;
  int pbase = fb * PPB;
  #pragma unroll
  for (int k = 0; k < 2; ++k) {
    int off = tid + (k << 9);
    int n = pbase + off;
    if (off < PPB && n < N_) {
      float c0 = coords[n * 3], c1 = coords[n * 3 + 1], c2 = coords[n * 3 + 2];
      float b5n = b5[n];
      float w5v[8];
      #pragma unroll
      for (int kk = 0; kk < 8; ++kk) w5v[kk] = W5[(size_t)kk * N_ + n];   // coalesced streams
      #pragma unroll
      for (int b = 0; b < BQ; ++b) {
        float px, py;
        projPxPy(c0, c1, c2, sR[b], ss[b], px, py);
        if (px >= -1.f && px < 256.f && py >= -1.f && py < 256.f) {
          int y0 = (int)floorf(py);
          int slab = (y0 < 0 ? 0 : y0) >> 3;
          int bin = b * NSLAB + slab;
          unsigned slot = atomicAdd(&scur[bin], 1u);
          if (slot < ENT_N) {                // paranoid OOB guard (exact counts => never hit)
            float delta = b5n;
            #pragma unroll
            for (int kk = 0; kk < 8; ++kk) delta = fmaf(sh[b][kk], w5v[kk], delta);
            entq[slot] = make_float2(__int_as_float(n), delta);
          }
        }
      }
    }
  }
}

// ---------------- scatter2: ALL quarters; one block per (q,bin); recompute px,py; INT LDS atomics ----------------
__global__ __launch_bounds__(512) void k_scatter2(const float2* __restrict__ ent,
                                                  const float* __restrict__ coords,
                                                  const float* __restrict__ Rbuf,
                                                  const float* __restrict__ shifts,
                                                  const unsigned* __restrict__ binBase,
                                                  const unsigned* __restrict__ totals,
                                                  float* __restrict__ img,
                                                  float* __restrict__ apron) {
  __shared__ int tile[9 * XSZ];          // 9 KB
  __shared__ float sA[8];                // sR row0/row1 + bx,by for THIS image
  int tid = threadIdx.x;
  int q = blockIdx.x >> 8;               // BINS_Q = 256
  int bin = blockIdx.x & 255;
  int b_local = bin >> 5;                // / NSLAB
  int s = bin & 31;
  int b_global = q * BQ + b_local;
  if (tid < 6)      sA[tid] = Rbuf[b_global * 9 + tid] * 100.f;
  else if (tid < 8) sA[tid] = 128.f - shifts[b_global * 2 + (tid - 6)];
  for (int i = tid; i < 9 * XSZ; i += 512) tile[i] = 0;
  __syncthreads();
  unsigned base = binBase[q * BINS_Q + bin];
  unsigned cntv = totals[q * BINS_Q + bin];
  if (base >= ENT_N) cntv = 0;
  else if (base + cntv > ENT_N) cntv = ENT_N - base;
  const float2* entq = ent + (size_t)q * ENT_N;
  int ybase = s << 3;
  for (unsigned i = tid; i < cntv; i += 512) {
    float2 e = entq[base + i];
    int n = __float_as_int(e.x);
    float delta = e.y;
    float c0 = coords[n * 3], c1 = coords[n * 3 + 1], c2 = coords[n * 3 + 2];
    float px, py;
    projPxPy(c0, c1, c2, sA, sA + 6, px, py);
    float x0f = floorf(px), y0f = floorf(py);
    float fx = px - x0f, fy = py - y0f;
    int x0 = (int)x0f;
    int r0 = (int)y0f - ybase;           // in [-1, 7]
    float wy0 = (1.f - fy) * delta * FP_SCALE;
    float wy1 = fy * delta * FP_SCALE;
    bool xl = (x0 >= 0), xr = (x0 <= 254);
    if (r0 >= 0) {
      int c0i = r0 * XSZ + x0;
      if (xl) atomicAdd(&tile[c0i], __float2int_rn((1.f - fx) * wy0));
      if (xr) atomicAdd(&tile[c0i + 1], __float2int_rn(fx * wy0));
    }
    int c1i = (r0 + 1) * XSZ + x0;       // r0+1 in [0,8] always in-tile
    if (xl) atomicAdd(&tile[c1i], __float2int_rn((1.f - fx) * wy1));
    if (xr) atomicAdd(&tile[c1i + 1], __float2int_rn(fx * wy1));
  }
  __syncthreads();
  float* imbase = img + (size_t)b_global * 65536 + (size_t)ybase * XSZ;
  for (int i = tid; i < 8 * XSZ; i += 512) imbase[i] = (float)tile[i] * FP_INV;
  if (tid < XSZ) apron[(size_t)(q * BINS_Q + bin) * XSZ + tid] = (float)tile[8 * XSZ + tid] * FP_INV;
}

// ---------------- apron fixup: add boundary rows ----------------
__global__ __launch_bounds__(256) void k_apron(const float* __restrict__ apron,
                                               float* __restrict__ img) {
  int bid = blockIdx.x;                 // b_global*32 + s
  int s = bid & 31;
  if (s == 31) return;                  // row 256 discarded
  int b = bid >> 5;
  int q = b >> 3, b_local = b & 7;
  int bin = b_local * NSLAB + s;
  int row = (s + 1) << 3;
  float* dst = img + (size_t)b * 65536 + (size_t)row * XSZ;
  dst[threadIdx.x] += apron[(size_t)(q * BINS_Q + bin) * XSZ + threadIdx.x];
}

// ---------------- separable Gaussian blur (zero-padded SAME) ----------------
__device__ __forceinline__ float bwv(int i) {
  const float bw[7] = {0.004433048f, 0.054005582f, 0.242036226f, 0.399050280f,
                       0.242036226f, 0.054005582f, 0.004433048f};
  return bw[i];
}

__global__ __launch_bounds__(256) void k_blurV(const float* __restrict__ in, float* __restrict__ out) {
  int i = blockIdx.x * 256 + threadIdx.x;
  int x = i & 255;
  int y = (i >> 8) & 255;
  const float* p = in + (i & ~65535);
  float s = 0.f;
  #pragma unroll
  for (int d = -3; d <= 3; ++d) {
    int yy = y + d;
    if ((unsigned)yy < XSZ) s += bwv(d + 3) * p[(yy << 8) + x];
  }
  out[i] = s;
}

__global__ __launch_bounds__(256) void k_blurH(const float* __restrict__ in, float* __restrict__ out) {
  int i = blockIdx.x * 256 + threadIdx.x;
  int x = i & 255;
  float s = 0.f;
  #pragma unroll
  for (int d = -3; d <= 3; ++d) {
    int xx = x + d;
    if ((unsigned)xx < XSZ) s += bwv(d + 3) * in[i + d];
  }
  out[i] = s;
}

// ---------------- FFT helpers: 256-pt, SoA in LDS, stride PADS ----------------
__device__ __forceinline__ void fft_dif_fwd(float* re, float* im, const float2* tw, int P, int tid) {
  for (int s = 7; s >= 0; --s) {
    __syncthreads();
    int half = 1 << s;
    for (int q = tid; q < (P << 7); q += 256) {
      int p = q >> 7, k = q & 127;
      int j = k & (half - 1);
      int i0 = ((k >> s) << (s + 1)) | j;
      int i1 = i0 + half;
      float* rp = re + p * PADS; float* ip = im + p * PADS;
      float ar = rp[i0], ai = ip[i0], br = rp[i1], bi = ip[i1];
      rp[i0] = ar + br; ip[i0] = ai + bi;
      float tr = ar - br, ti = ai - bi;
      float2 w = tw[j << (7 - s)];
      rp[i1] = tr * w.x - ti * w.y;
      ip[i1] = tr * w.y + ti * w.x;
    }
  }
  __syncthreads();
}

__device__ __forceinline__ void fft_dit_inv(float* re, float* im, const float2* tw, int P, int tid) {
  for (int s = 0; s <= 7; ++s) {
    __syncthreads();
    int half = 1 << s;
    for (int q = tid; q < (P << 7); q += 256) {
      int p = q >> 7, k = q & 127;
      int j = k & (half - 1);
      int i0 = ((k >> s) << (s + 1)) | j;
      int i1 = i0 + half;
      float* rp = re + p * PADS; float* ip = im + p * PADS;
      float2 w = tw[j << (7 - s)];               // conj -> (w.x, -w.y)
      float br = rp[i1], bi = ip[i1];
      float tr = br * w.x + bi * w.y;
      float ti = bi * w.x - br * w.y;
      float ar = rp[i0], ai = ip[i0];
      rp[i0] = ar + tr; ip[i0] = ai + ti;
      rp[i1] = ar - tr; ip[i1] = ai - ti;
    }
  }
  __syncthreads();
}

__device__ __forceinline__ void tw_init(float2* tw, int tid) {
  for (int k = tid; k < 128; k += 256) {
    float s_, c_;
    sincosf(-6.2831853071795864769f * (float)k / 256.0f, &s_, &c_);
    tw[k] = make_float2(c_, s_);
  }
}

// F1: row FFT (over x), DIF, store transposed: Fc[b][i][y] holds kx=rev8(i)
__global__ __launch_bounds__(256) void k_fft1(const float* __restrict__ img, float2* __restrict__ Fc) {
  __shared__ float re[16 * PADS], im[16 * PADS];
  __shared__ float2 tw[128];
  int tid = threadIdx.x;
  int b = blockIdx.x >> 4;
  int y0 = (blockIdx.x & 15) << 4;
  tw_init(tw, tid);
  const float* src = img + (size_t)b * 65536 + (size_t)y0 * 256;
  for (int q = tid; q < 4096; q += 256) {
    int j = q >> 8, x = q & 255;
    re[j * PADS + x] = src[j * 256 + x];
    im[j * PADS + x] = 0.f;
  }
  fft_dif_fwd(re, im, tw, 16, tid);
  float2* dst = Fc + (size_t)b * 65536;
  for (int q = tid; q < 4096; q += 256) {
    int j = q & 15, i = q >> 4;
    dst[(size_t)i * 256 + y0 + j] = make_float2(re[j * PADS + i], im[j * PADS + i]);
  }
}

// F2: column FFT (over y) DIF fwd, * ctf_ext, DIT inverse; in-place on Fc rows
__global__ __launch_bounds__(256) void k_fft2(float2* __restrict__ Fc, const float* __restrict__ ctf) {
  __shared__ float re[4 * PADS], im[4 * PADS];
  __shared__ float2 tw[128];
  int tid = threadIdx.x;
  int b = blockIdx.x >> 6;
  int r0 = (blockIdx.x & 63) << 2;
  tw_init(tw, tid);
  float2* base = Fc + (size_t)b * 65536 + (size_t)r0 * 256;
  for (int q = tid; q < 1024; q += 256) {
    int p = q >> 8, y = q & 255;
    float2 v = base[p * 256 + y];
    re[p * PADS + y] = v.x; im[p * PADS + y] = v.y;
  }
  fft_dif_fwd(re, im, tw, 4, tid);
  for (int q = tid; q < 1024; q += 256) {
    int p = q >> 8, iy = q & 255;
    int kx = rev8(r0 + p), ky = rev8(iy);
    float c;
    if (kx <= 128) c = ctf[((size_t)b * 256 + ky) * 129 + kx];
    else           c = ctf[((size_t)b * 256 + ((256 - ky) & 255)) * 129 + (256 - kx)];
    re[p * PADS + iy] *= c; im[p * PADS + iy] *= c;
  }
  fft_dit_inv(re, im, tw, 4, tid);
  for (int q = tid; q < 1024; q += 256) {
    int p = q >> 8, y = q & 255;
    base[p * 256 + y] = make_float2(re[p * PADS + y], im[p * PADS + y]);
  }
}

// F3: inverse row FFT (over kx). Rows of Fc are already bitrev-ordered in kx -> DIT direct.
__global__ __launch_bounds__(256) void k_fft3(const float2* __restrict__ Fc, float* __restrict__ out) {
  __shared__ float re[16 * PADS], im[16 * PADS];
  __shared__ float2 tw[128];
  int tid = threadIdx.x;
  int b = blockIdx.x >> 4;
  int y0 = (blockIdx.x & 15) << 4;
  tw_init(tw, tid);
  const float2* src = Fc + (size_t)b * 65536;
  for (int q = tid; q < 4096; q += 256) {
    int j = q & 15, r = q >> 4;
    float2 v = src[(size_t)r * 256 + y0 + j];
    re[j * PADS + r] = v.x; im[j * PADS + r] = v.y;
  }
  fft_dit_inv(re, im, tw, 16, tid);
  float* dst = out + (size_t)b * 65536 + (size_t)y0 * 256;
  for (int q = tid; q < 4096; q += 256) {
    int j = q >> 8, x = q & 255;
    dst[j * 256 + x] = re[j * PADS + x] * (1.f / 65536.f);
  }
}

extern "C" void kernel_launch(void* const* d_in, const int* in_sizes, int n_in,
                              void* d_out, int out_size, void* d_ws, size_t ws_size,
                              hipStream_t stream) {
  const float* rows   = (const float*)d_in[0];
  const float* shifts = (const float*)d_in[1];
  const float* coords = (const float*)d_in[2];
  const float* W1     = (const float*)d_in[3];
  const float* b1     = (const float*)d_in[4];
  const float* Wh     = (const float*)d_in[5];
  const float* bh     = (const float*)d_in[6];
  const float* W5     = (const float*)d_in[7];
  const float* b5     = (const float*)d_in[8];
  const float* ctf    = (const float*)d_in[9];
  float* out = (float*)d_out;
  char* ws = (char*)d_ws;

  float*          partial = (float*)(ws + OFF_PART);
  float*          hbuf    = (float*)(ws + OFF_H);
  float*          Rbuf    = (float*)(ws + OFF_R);
  unsigned short* cnt     = (unsigned short*)(ws + OFF_CNT);
  unsigned*       intra   = (unsigned*)(ws + OFF_INTRA);
  unsigned*       totals  = (unsigned*)(ws + OFF_TOT);
  unsigned*       binBase = (unsigned*)(ws + OFF_BB);
  float*          apron   = (float*)(ws + OFF_APR);
  float*          img     = (float*)(ws + OFF_IMG);
  float2*         ent     = (float2*)(ws + OFF_ENT);
  float*          tmp     = (float*)(ws + OFF_TMP);
  float2*         Fc      = (float2*)(ws + OFF_FC);

  k_reduceT<<<256, 256, 0, stream>>>(coords, W1, partial);
  k_batch<<<1, 128, 0, stream>>>(partial, rows, b1, Wh, bh, hbuf, Rbuf);
  k_count<<<NQ * FILLB, 512, 0, stream>>>(coords, Rbuf, shifts, cnt);
  k_offA<<<NQ * BINS_Q, 256, 0, stream>>>(cnt, intra, totals);
  k_offB<<<NQ, 256, 0, stream>>>(totals, binBase);
  k_fill2<<<NQ * FILLB, 512, 0, stream>>>(coords, W5, b5, hbuf, Rbuf, shifts,
                                          intra, binBase, ent);
  k_scatter2<<<NQ * BINS_Q, 512, 0, stream>>>(ent, coords, Rbuf, shifts,
                                              binBase, totals, img, apron);
  k_apron<<<B_ * NSLAB, 256, 0, stream>>>(apron, img);
  k_blurV<<<B_ * XSZ * XSZ / 256, 256, 0, stream>>>(img, tmp);
  k_blurH<<<B_ * XSZ * XSZ / 256, 256, 0, stream>>>(tmp, img);
  k_fft1<<<B_ * 16, 256, 0, stream>>>(img, Fc);
  k_fft2<<<B_ * 64, 256, 0, stream>>>(Fc, ctf);
  k_fft3<<<B_ * 16, 256, 0, stream>>>(Fc, out);
}

// Round 20
// 166.821 us; speedup vs baseline: 2.5023x; 1.0765x over previous
//
#include <hip/hip_runtime.h>
#include <math.h>

constexpr int B_  = 32;
constexpr int N_  = 200000;
constexpr int XSZ = 256;
constexpr int PADS = 257;                   // SoA LDS row stride (floats)

// scatter binning config
constexpr int NQ = 4;                        // quarters (image groups)
constexpr int BQ = 8;                        // images per quarter
constexpr int NSLAB = 32;                    // 8-row slabs per image
constexpr int BINS_Q = BQ * NSLAB;           // 256 bins per quarter
constexpr int FILLB = 256;                   // fill blocks per quarter
constexpr int PPB = 782;                     // points per fill block (256*782 >= 200000)
constexpr unsigned ENT_N = 1600000;          // HARD upper bound per quarter: N_*BQ

// fixed-point accumulation (native int LDS atomics)
constexpr float FP_SCALE = 4194304.f;        // 2^22
constexpr float FP_INV   = 1.f / 4194304.f;

// workspace layout (bytes) — total ~65 MB (ws_size = 256 MiB per harness poison fills)
constexpr size_t OFF_PART  = 0;                                   // 73728
constexpr size_t OFF_H     = 73728;                               // 1024
constexpr size_t OFF_R     = 74752;                               // 2048 pad
constexpr size_t OFF_CNT   = 76800;                               // u16: 4*256*256*2 = 524288
constexpr size_t OFF_INTRA = OFF_CNT + 524288;                    // u32: 1048576
constexpr size_t OFF_TOT   = OFF_INTRA + 1048576;                 // 4096
constexpr size_t OFF_BB    = OFF_TOT + 4096;                      // 4096
constexpr size_t OFF_APR   = OFF_BB + 4096;                       // 4*256*256*4 = 1048576
constexpr size_t OFF_IMG   = OFF_APR + 1048576;                   // 8388608
constexpr size_t OFF_ENT   = OFF_IMG + 8388608;                   // entries: 4 quarters x 12.8 MB
// post-scatter overlay (entries dead after k_scatter2):
constexpr size_t OFF_FC    = OFF_ENT;                             // 16.8 MB float2

__device__ __forceinline__ int rev8(int x) { return (int)(__brev((unsigned)x) >> 24); }

// shared projection: EXPLICIT fmaf so k_count, k_fill2, k_scatter2 emit identical FP sequences
__device__ __forceinline__ void projPxPy(float c0, float c1, float c2,
                                         const float* sRb, const float* ssb,
                                         float& px, float& py) {
  px = fmaf(sRb[0], c0, fmaf(sRb[1], c1, fmaf(sRb[2], c2, ssb[0])));
  py = fmaf(sRb[3], c0, fmaf(sRb[4], c1, fmaf(sRb[5], c2, ssb[1])));
}

// ---------------- T reduction: T[j,i,k] = sum_n coords[n,j] * W1[3n+i,k] ----------------
__global__ __launch_bounds__(256) void k_reduceT(const float* __restrict__ coords,
                                                 const float* __restrict__ W1,
                                                 float* __restrict__ partial) {
  float acc[72];
  #pragma unroll
  for (int t = 0; t < 72; ++t) acc[t] = 0.f;
  int idx = blockIdx.x * 256 + threadIdx.x;
  for (int n = idx; n < N_; n += 256 * 256) {
    float c0 = coords[n * 3 + 0], c1 = coords[n * 3 + 1], c2 = coords[n * 3 + 2];
    const float4* w4 = reinterpret_cast<const float4*>(W1 + (size_t)n * 24);
    #pragma unroll
    for (int i = 0; i < 3; ++i) {
      float4 wa = w4[i * 2 + 0], wb = w4[i * 2 + 1];
      float wv[8] = {wa.x, wa.y, wa.z, wa.w, wb.x, wb.y, wb.z, wb.w};
      #pragma unroll
      for (int k = 0; k < 8; ++k) {
        acc[i * 8 + k]      += c0 * wv[k];
        acc[24 + i * 8 + k] += c1 * wv[k];
        acc[48 + i * 8 + k] += c2 * wv[k];
      }
    }
  }
  #pragma unroll
  for (int t = 0; t < 72; ++t) {
    float v = acc[t];
    for (int off = 32; off > 0; off >>= 1) v += __shfl_down(v, off, 64);
    acc[t] = v;
  }
  __shared__ float sred[4][72];
  int lane = threadIdx.x & 63, wv_ = threadIdx.x >> 6;
  if (lane == 0) {
    #pragma unroll
    for (int t = 0; t < 72; ++t) sred[wv_][t] = acc[t];
  }
  __syncthreads();
  if (threadIdx.x < 72) {
    int t = threadIdx.x;
    partial[blockIdx.x * 72 + t] = sred[0][t] + sred[1][t] + sred[2][t] + sred[3][t];
  }
}

// ---------------- per-batch: finalize T, rotation matrices, MLP head ----------------
__global__ __launch_bounds__(128) void k_batch(const float* __restrict__ partial,
                                               const float* __restrict__ rows,
                                               const float* __restrict__ b1,
                                               const float* __restrict__ Wh,
                                               const float* __restrict__ bh,
                                               float* __restrict__ hbuf,
                                               float* __restrict__ Rbuf) {
  __shared__ float T[72];
  int tid = threadIdx.x;
  if (tid < 72) {
    double s = 0.0;
    for (int i = 0; i < 256; ++i) s += (double)partial[i * 72 + tid];
    T[tid] = (float)s;
  }
  __syncthreads();
  if (tid < B_) {
    int b = tid;
    float al = rows[b * 3 + 0], be = rows[b * 3 + 1], ga = rows[b * 3 + 2];
    float sa, ca, sb, cb, sg, cg;
    sincosf(al, &sa, &ca); sincosf(be, &sb, &cb); sincosf(ga, &sg, &cg);
    float R[3][3];
    R[0][0] = ca * cb * cg - sa * sg; R[0][1] = -ca * cb * sg - sa * cg; R[0][2] = ca * sb;
    R[1][0] = sa * cb * cg + ca * sg; R[1][1] = -sa * cb * sg + ca * cg; R[1][2] = sa * sb;
    R[2][0] = -sb * cg;               R[2][1] = sb * sg;                 R[2][2] = cb;
    float h[8];
    #pragma unroll
    for (int k = 0; k < 8; ++k) {
      float z = b1[k];
      #pragma unroll
      for (int i = 0; i < 3; ++i)
        #pragma unroll
        for (int j = 0; j < 3; ++j)
          z += R[i][j] * T[(j * 3 + i) * 8 + k];
      h[k] = sinf(30.f * z);
    }
    for (int l = 0; l < 3; ++l) {
      float nh[8];
      #pragma unroll
      for (int k2 = 0; k2 < 8; ++k2) {
        float z = bh[l * 8 + k2];
        #pragma unroll
        for (int k1 = 0; k1 < 8; ++k1) z += h[k1] * Wh[l * 64 + k1 * 8 + k2];
        nh[k2] = sinf(z);
      }
      #pragma unroll
      for (int k = 0; k < 8; ++k) h[k] = nh[k];
    }
    #pragma unroll
    for (int k = 0; k < 8; ++k) hbuf[b * 8 + k] = h[k];
    #pragma unroll
    for (int i = 0; i < 3; ++i)
      #pragma unroll
      for (int j = 0; j < 3; ++j) Rbuf[b * 9 + i * 3 + j] = R[i][j];
  }
}

// ---------------- count: per (quarter, fill-block, bin) histogram — ALL quarters ----------------
__global__ __launch_bounds__(512) void k_count(const float* __restrict__ coords,
                                               const float* __restrict__ Rbuf,
                                               const float* __restrict__ shifts,
                                               unsigned short* __restrict__ cnt) {
  __shared__ float sR[BQ][6];
  __shared__ float ss[BQ][2];
  __shared__ unsigned hist[BINS_Q];
  int tid = threadIdx.x;
  int q = blockIdx.x >> 8;            // FILLB = 256
  int fb = blockIdx.x & 255;
  if (tid < BQ) {
    int b = q * BQ + tid;
    sR[tid][0] = Rbuf[b * 9 + 0] * 100.f; sR[tid][1] = Rbuf[b * 9 + 1] * 100.f; sR[tid][2] = Rbuf[b * 9 + 2] * 100.f;
    sR[tid][3] = Rbuf[b * 9 + 3] * 100.f; sR[tid][4] = Rbuf[b * 9 + 4] * 100.f; sR[tid][5] = Rbuf[b * 9 + 5] * 100.f;
    ss[tid][0] = 128.f - shifts[b * 2 + 0];
    ss[tid][1] = 128.f - shifts[b * 2 + 1];
  }
  if (tid < BINS_Q) hist[tid] = 0;
  __syncthreads();
  int pbase = fb * PPB;
  #pragma unroll
  for (int k = 0; k < 2; ++k) {
    int off = tid + (k << 9);
    int n = pbase + off;
    if (off < PPB && n < N_) {
      float c0 = coords[n * 3], c1 = coords[n * 3 + 1], c2 = coords[n * 3 + 2];
      #pragma unroll
      for (int b = 0; b < BQ; ++b) {
        float px, py;
        projPxPy(c0, c1, c2, sR[b], ss[b], px, py);
        if (px >= -1.f && px < 256.f && py >= -1.f && py < 256.f) {
          int y0 = (int)floorf(py);
          int slab = (y0 < 0 ? 0 : y0) >> 3;
          atomicAdd(&hist[b * NSLAB + slab], 1u);
        }
      }
    }
  }
  __syncthreads();
  if (tid < BINS_Q) cnt[(size_t)blockIdx.x * BINS_Q + tid] = (unsigned short)hist[tid];
}

// ---------------- offA: per-(quarter,bin) exclusive scan over 256 fill-blocks ----------------
__global__ __launch_bounds__(256) void k_offA(const unsigned short* __restrict__ cnt,
                                              unsigned* __restrict__ intra,
                                              unsigned* __restrict__ totals) {
  int q = blockIdx.x >> 8;            // BINS_Q = 256
  int bin = blockIdx.x & 255;
  int t = threadIdx.x;                // fill-block index
  size_t cbase = ((size_t)q * FILLB + t) * BINS_Q + bin;
  unsigned orig = cnt[cbase];
  unsigned v = orig;
  int lane = t & 63, wid = t >> 6;
  #pragma unroll
  for (int d = 1; d < 64; d <<= 1) { unsigned u = __shfl_up(v, d, 64); if (lane >= d) v += u; }
  __shared__ unsigned wsum[4];
  if (lane == 63) wsum[wid] = v;
  __syncthreads();
  unsigned woff = 0;
  #pragma unroll
  for (int w = 0; w < 4; ++w) if (w < wid) woff += wsum[w];
  intra[cbase] = woff + v - orig;
  if (t == 255) totals[q * BINS_Q + bin] = woff + v;
}

// ---------------- offB: per-quarter exclusive scan of 256 bin totals ----------------
__global__ __launch_bounds__(256) void k_offB(const unsigned* __restrict__ totals,
                                              unsigned* __restrict__ binBase) {
  int q = blockIdx.x;
  int t = threadIdx.x;
  unsigned orig = totals[q * BINS_Q + t];
  unsigned v = orig;
  int lane = t & 63, wid = t >> 6;
  #pragma unroll
  for (int d = 1; d < 64; d <<= 1) { unsigned u = __shfl_up(v, d, 64); if (lane >= d) v += u; }
  __shared__ unsigned wsum[4];
  if (lane == 63) wsum[wid] = v;
  __syncthreads();
  unsigned woff = 0;
  #pragma unroll
  for (int w = 0; w < 4; ++w) if (w < wid) woff += wsum[w];
  binBase[q * BINS_Q + t] = woff + v - orig;
}

// ---------------- fill2: ALL quarters; entries = float2{n_bits, delta}, 8B single store ----------------
__global__ __launch_bounds__(512) void k_fill2(const float* __restrict__ coords,
                                               const float* __restrict__ W5,
                                               const float* __restrict__ b5,
                                               const float* __restrict__ hbuf,
                                               const float* __restrict__ Rbuf,
                                               const float* __restrict__ shifts,
                                               const unsigned* __restrict__ intra,
                                               const unsigned* __restrict__ binBase,
                                               float2* __restrict__ ent) {
  __shared__ float sR[BQ][6];
  __shared__ float ss[BQ][2];
  __shared__ float sh[BQ][8];
  __shared__ unsigned scur[BINS_Q];
  int tid = threadIdx.x;
  int q = blockIdx.x >> 8;            // FILLB = 256
  int fb = blockIdx.x & 255;
  if (tid < BQ) {
    int b = q * BQ + tid;
    sR[tid][0] = Rbuf[b * 9 + 0] * 100.f; sR[tid][1] = Rbuf[b * 9 + 1] * 100.f; sR[tid][2] = Rbuf[b * 9 + 2] * 100.f;
    sR[tid][3] = Rbuf[b * 9 + 3] * 100.f; sR[tid][4] = Rbuf[b * 9 + 4] * 100.f; sR[tid][5] = Rbuf[b * 9 + 5] * 100.f;
    ss[tid][0] = 128.f - shifts[b * 2 + 0];
    ss[tid][1] = 128.f - shifts[b * 2 + 1];
    #pragma unroll
    for (int k = 0; k < 8; ++k) sh[tid][k] = hbuf[b * 8 + k];
  }
  if (tid < BINS_Q)
    scur[tid] = binBase[q * BINS_Q + tid] + intra[((size_t)q * FILLB + fb) * BINS_Q + tid];
  __syncthreads();
  float2* entq = ent + (size_t)q * ENT_N;
  int pbase = fb * PPB;
  #pragma unroll
  for (int k = 0; k < 2; ++k) {
    int off = tid + (k << 9);
    int n = pbase + off;
    if (off < PPB && n < N_) {
      float c0 = coords[n * 3], c1 = coords[n * 3 + 1], c2 = coords[n * 3 + 2];
      float b5n = b5[n];
      float w5v[8];
      #pragma unroll
      for (int kk = 0; kk < 8; ++kk) w5v[kk] = W5[(size_t)kk * N_ + n];   // coalesced streams
      #pragma unroll
      for (int b = 0; b < BQ; ++b) {
        float px, py;
        projPxPy(c0, c1, c2, sR[b], ss[b], px, py);
        if (px >= -1.f && px < 256.f && py >= -1.f && py < 256.f) {
          int y0 = (int)floorf(py);
          int slab = (y0 < 0 ? 0 : y0) >> 3;
          int bin = b * NSLAB + slab;
          unsigned slot = atomicAdd(&scur[bin], 1u);
          if (slot < ENT_N) {                // paranoid OOB guard (exact counts => never hit)
            float delta = b5n;
            #pragma unroll
            for (int kk = 0; kk < 8; ++kk) delta = fmaf(sh[b][kk], w5v[kk], delta);
            entq[slot] = make_float2(__int_as_float(n), delta);
          }
        }
      }
    }
  }
}

// ---------------- scatter2: one block per (q,bin); 2x ILP; recompute px,py; INT LDS atomics ----------------
__global__ __launch_bounds__(512) void k_scatter2(const float2* __restrict__ ent,
                                                  const float* __restrict__ coords,
                                                  const float* __restrict__ Rbuf,
                                                  const float* __restrict__ shifts,
                                                  const unsigned* __restrict__ binBase,
                                                  const unsigned* __restrict__ totals,
                                                  float* __restrict__ img,
                                                  float* __restrict__ apron) {
  __shared__ int tile[9 * XSZ];          // 9 KB
  __shared__ float sA[8];                // sR row0/row1 + bx,by for THIS image
  int tid = threadIdx.x;
  int q = blockIdx.x >> 8;               // BINS_Q = 256
  int bin = blockIdx.x & 255;
  int b_local = bin >> 5;                // / NSLAB
  int s = bin & 31;
  int b_global = q * BQ + b_local;
  if (tid < 6)      sA[tid] = Rbuf[b_global * 9 + tid] * 100.f;
  else if (tid < 8) sA[tid] = 128.f - shifts[b_global * 2 + (tid - 6)];
  for (int i = tid; i < 9 * XSZ; i += 512) tile[i] = 0;
  __syncthreads();
  unsigned base = binBase[q * BINS_Q + bin];
  unsigned cntv = totals[q * BINS_Q + bin];
  if (base >= ENT_N) cntv = 0;
  else if (base + cntv > ENT_N) cntv = ENT_N - base;
  const float2* entq = ent + (size_t)q * ENT_N;
  int ybase = s << 3;

  auto doEntry = [&](float c0, float c1, float c2, float delta) {
    float px, py;
    projPxPy(c0, c1, c2, sA, sA + 6, px, py);
    float x0f = floorf(px), y0f = floorf(py);
    float fx = px - x0f, fy = py - y0f;
    int x0 = (int)x0f;
    int r0 = (int)y0f - ybase;           // in [-1, 7]
    float wy0 = (1.f - fy) * delta * FP_SCALE;
    float wy1 = fy * delta * FP_SCALE;
    bool xl = (x0 >= 0), xr = (x0 <= 254);
    if (r0 >= 0) {
      int c0i = r0 * XSZ + x0;
      if (xl) atomicAdd(&tile[c0i], __float2int_rn((1.f - fx) * wy0));
      if (xr) atomicAdd(&tile[c0i + 1], __float2int_rn(fx * wy0));
    }
    int c1i = (r0 + 1) * XSZ + x0;       // r0+1 in [0,8] always in-tile
    if (xl) atomicAdd(&tile[c1i], __float2int_rn((1.f - fx) * wy1));
    if (xr) atomicAdd(&tile[c1i + 1], __float2int_rn(fx * wy1));
  };

  for (unsigned i = tid; i < cntv; i += 1024) {
    unsigned i1 = i + 512;
    bool v1 = i1 < cntv;
    float2 e0 = entq[base + i];
    float2 e1 = v1 ? entq[base + i1] : make_float2(0.f, 0.f);
    int n0 = __float_as_int(e0.x);
    float c00 = coords[n0 * 3], c01 = coords[n0 * 3 + 1], c02 = coords[n0 * 3 + 2];
    float c10 = 0.f, c11 = 0.f, c12 = 0.f;
    if (v1) {
      int n1 = __float_as_int(e1.x);
      c10 = coords[n1 * 3]; c11 = coords[n1 * 3 + 1]; c12 = coords[n1 * 3 + 2];
    }
    doEntry(c00, c01, c02, e0.y);
    if (v1) doEntry(c10, c11, c12, e1.y);
  }
  __syncthreads();
  float* imbase = img + (size_t)b_global * 65536 + (size_t)ybase * XSZ;
  for (int i = tid; i < 8 * XSZ; i += 512) imbase[i] = (float)tile[i] * FP_INV;
  if (tid < XSZ) apron[(size_t)(q * BINS_Q + bin) * XSZ + tid] = (float)tile[8 * XSZ + tid] * FP_INV;
}

// ---------------- apron fixup: add boundary rows ----------------
__global__ __launch_bounds__(256) void k_apron(const float* __restrict__ apron,
                                               float* __restrict__ img) {
  int bid = blockIdx.x;                 // b_global*32 + s
  int s = bid & 31;
  if (s == 31) return;                  // row 256 discarded
  int b = bid >> 5;
  int q = b >> 3, b_local = b & 7;
  int bin = b_local * NSLAB + s;
  int row = (s + 1) << 3;
  float* dst = img + (size_t)b * 65536 + (size_t)row * XSZ;
  dst[threadIdx.x] += apron[(size_t)(q * BINS_Q + bin) * XSZ + threadIdx.x];
}

// ---------------- blur weights ----------------
__device__ __forceinline__ float bwv(int i) {
  const float bw[7] = {0.004433048f, 0.054005582f, 0.242036226f, 0.399050280f,
                       0.242036226f, 0.054005582f, 0.004433048f};
  return bw[i];
}

// ---------------- FFT helpers: 256-pt, SoA in LDS, stride PADS ----------------
__device__ __forceinline__ void fft_dif_fwd(float* re, float* im, const float2* tw, int P, int tid) {
  for (int s = 7; s >= 0; --s) {
    __syncthreads();
    int half = 1 << s;
    for (int q = tid; q < (P << 7); q += 256) {
      int p = q >> 7, k = q & 127;
      int j = k & (half - 1);
      int i0 = ((k >> s) << (s + 1)) | j;
      int i1 = i0 + half;
      float* rp = re + p * PADS; float* ip = im + p * PADS;
      float ar = rp[i0], ai = ip[i0], br = rp[i1], bi = ip[i1];
      rp[i0] = ar + br; ip[i0] = ai + bi;
      float tr = ar - br, ti = ai - bi;
      float2 w = tw[j << (7 - s)];
      rp[i1] = tr * w.x - ti * w.y;
      ip[i1] = tr * w.y + ti * w.x;
    }
  }
  __syncthreads();
}

__device__ __forceinline__ void fft_dit_inv(float* re, float* im, const float2* tw, int P, int tid) {
  for (int s = 0; s <= 7; ++s) {
    __syncthreads();
    int half = 1 << s;
    for (int q = tid; q < (P << 7); q += 256) {
      int p = q >> 7, k = q & 127;
      int j = k & (half - 1);
      int i0 = ((k >> s) << (s + 1)) | j;
      int i1 = i0 + half;
      float* rp = re + p * PADS; float* ip = im + p * PADS;
      float2 w = tw[j << (7 - s)];               // conj -> (w.x, -w.y)
      float br = rp[i1], bi = ip[i1];
      float tr = br * w.x + bi * w.y;
      float ti = bi * w.x - br * w.y;
      float ar = rp[i0], ai = ip[i0];
      rp[i0] = ar + tr; ip[i0] = ai + ti;
      rp[i1] = ar - tr; ip[i1] = ai - ti;
    }
  }
  __syncthreads();
}

__device__ __forceinline__ void tw_init(float2* tw, int tid) {
  for (int k = tid; k < 128; k += 256) {
    float s_, c_;
    sincosf(-6.2831853071795864769f * (float)k / 256.0f, &s_, &c_);
    tw[k] = make_float2(c_, s_);
  }
}

// F1b: FUSED separable blur + row FFT (over x), DIF, store transposed.
// LDS: raw[22*256] (later aliased by re[16*PADS]) | bv[16*256] | im[16*PADS]
__global__ __launch_bounds__(256) void k_fft1b(const float* __restrict__ img, float2* __restrict__ Fc) {
  __shared__ float smem[13840];
  __shared__ float2 tw[128];
  float* raw = smem;               // 22*256 = 5632 floats
  float* bv  = smem + 5632;        // 16*256 = 4096 floats
  float* re  = smem;               // 16*257 = 4112 floats (aliases raw, dead after blurV)
  float* im  = smem + 9728;        // 16*257 = 4112 floats
  int tid = threadIdx.x;
  int b = blockIdx.x >> 4;
  int y0 = (blockIdx.x & 15) << 4;
  tw_init(tw, tid);
  const float* src = img + (size_t)b * 65536;
  for (int q = tid; q < 22 * 256; q += 256) {
    int j = q >> 8, x = q & 255;
    int y = y0 - 3 + j;
    raw[q] = ((unsigned)y < 256u) ? src[y * 256 + x] : 0.f;
  }
  __syncthreads();
  // vertical blur: bv[r][x] = sum_d w[d] * raw[r+d][x]  (offset d-3 rel. to row y0+r)
  for (int q = tid; q < 4096; q += 256) {
    int r = q >> 8, x = q & 255;
    float s = 0.f;
    #pragma unroll
    for (int d = 0; d < 7; ++d) s += bwv(d) * raw[(r + d) * 256 + x];
    bv[q] = s;
  }
  __syncthreads();
  // horizontal blur into re (aliases dead raw); zero im
  for (int q = tid; q < 4096; q += 256) {
    int r = q >> 8, x = q & 255;
    float s = 0.f;
    #pragma unroll
    for (int e = -3; e <= 3; ++e) {
      int xx = x + e;
      if ((unsigned)xx < 256u) s += bwv(e + 3) * bv[r * 256 + xx];
    }
    re[r * PADS + x] = s;
    im[r * PADS + x] = 0.f;
  }
  fft_dif_fwd(re, im, tw, 16, tid);   // begins with __syncthreads
  float2* dst = Fc + (size_t)b * 65536;
  for (int q = tid; q < 4096; q += 256) {
    int j = q & 15, i = q >> 4;
    dst[(size_t)i * 256 + y0 + j] = make_float2(re[j * PADS + i], im[j * PADS + i]);
  }
}

// F2: column FFT (over y) DIF fwd, * ctf_ext, DIT inverse; in-place on Fc rows
__global__ __launch_bounds__(256) void k_fft2(float2* __restrict__ Fc, const float* __restrict__ ctf) {
  __shared__ float re[4 * PADS], im[4 * PADS];
  __shared__ float2 tw[128];
  int tid = threadIdx.x;
  int b = blockIdx.x >> 6;
  int r0 = (blockIdx.x & 63) << 2;
  tw_init(tw, tid);
  float2* base = Fc + (size_t)b * 65536 + (size_t)r0 * 256;
  for (int q = tid; q < 1024; q += 256) {
    int p = q >> 8, y = q & 255;
    float2 v = base[p * 256 + y];
    re[p * PADS + y] = v.x; im[p * PADS + y] = v.y;
  }
  fft_dif_fwd(re, im, tw, 4, tid);
  for (int q = tid; q < 1024; q += 256) {
    int p = q >> 8, iy = q & 255;
    int kx = rev8(r0 + p), ky = rev8(iy);
    float c;
    if (kx <= 128) c = ctf[((size_t)b * 256 + ky) * 129 + kx];
    else           c = ctf[((size_t)b * 256 + ((256 - ky) & 255)) * 129 + (256 - kx)];
    re[p * PADS + iy] *= c; im[p * PADS + iy] *= c;
  }
  fft_dit_inv(re, im, tw, 4, tid);
  for (int q = tid; q < 1024; q += 256) {
    int p = q >> 8, y = q & 255;
    base[p * 256 + y] = make_float2(re[p * PADS + y], im[p * PADS + y]);
  }
}

// F3: inverse row FFT (over kx). Rows of Fc are already bitrev-ordered in kx -> DIT direct.
__global__ __launch_bounds__(256) void k_fft3(const float2* __restrict__ Fc, float* __restrict__ out) {
  __shared__ float re[16 * PADS], im[16 * PADS];
  __shared__ float2 tw[128];
  int tid = threadIdx.x;
  int b = blockIdx.x >> 4;
  int y0 = (blockIdx.x & 15) << 4;
  tw_init(tw, tid);
  const float2* src = Fc + (size_t)b * 65536;
  for (int q = tid; q < 4096; q += 256) {
    int j = q & 15, r = q >> 4;
    float2 v = src[(size_t)r * 256 + y0 + j];
    re[j * PADS + r] = v.x; im[j * PADS + r] = v.y;
  }
  fft_dit_inv(re, im, tw, 16, tid);
  float* dst = out + (size_t)b * 65536 + (size_t)y0 * 256;
  for (int q = tid; q < 4096; q += 256) {
    int j = q >> 8, x = q & 255;
    dst[j * 256 + x] = re[j * PADS + x] * (1.f / 65536.f);
  }
}

extern "C" void kernel_launch(void* const* d_in, const int* in_sizes, int n_in,
                              void* d_out, int out_size, void* d_ws, size_t ws_size,
                              hipStream_t stream) {
  const float* rows   = (const float*)d_in[0];
  const float* shifts = (const float*)d_in[1];
  const float* coords = (const float*)d_in[2];
  const float* W1     = (const float*)d_in[3];
  const float* b1     = (const float*)d_in[4];
  const float* Wh     = (const float*)d_in[5];
  const float* bh     = (const float*)d_in[6];
  const float* W5     = (const float*)d_in[7];
  const float* b5     = (const float*)d_in[8];
  const float* ctf    = (const float*)d_in[9];
  float* out = (float*)d_out;
  char* ws = (char*)d_ws;

  float*          partial = (float*)(ws + OFF_PART);
  float*          hbuf    = (float*)(ws + OFF_H);
  float*          Rbuf    = (float*)(ws + OFF_R);
  unsigned short* cnt     = (unsigned short*)(ws + OFF_CNT);
  unsigned*       intra   = (unsigned*)(ws + OFF_INTRA);
  unsigned*       totals  = (unsigned*)(ws + OFF_TOT);
  unsigned*       binBase = (unsigned*)(ws + OFF_BB);
  float*          apron   = (float*)(ws + OFF_APR);
  float*          img     = (float*)(ws + OFF_IMG);
  float2*         ent     = (float2*)(ws + OFF_ENT);
  float2*         Fc      = (float2*)(ws + OFF_FC);

  k_reduceT<<<256, 256, 0, stream>>>(coords, W1, partial);
  k_batch<<<1, 128, 0, stream>>>(partial, rows, b1, Wh, bh, hbuf, Rbuf);
  k_count<<<NQ * FILLB, 512, 0, stream>>>(coords, Rbuf, shifts, cnt);
  k_offA<<<NQ * BINS_Q, 256, 0, stream>>>(cnt, intra, totals);
  k_offB<<<NQ, 256, 0, stream>>>(totals, binBase);
  k_fill2<<<NQ * FILLB, 512, 0, stream>>>(coords, W5, b5, hbuf, Rbuf, shifts,
                                          intra, binBase, ent);
  k_scatter2<<<NQ * BINS_Q, 512, 0, stream>>>(ent, coords, Rbuf, shifts,
                                              binBase, totals, img, apron);
  k_apron<<<B_ * NSLAB, 256, 0, stream>>>(apron, img);
  k_fft1b<<<B_ * 16, 256, 0, stream>>>(img, Fc);
  k_fft2<<<B_ * 64, 256, 0, stream>>>(Fc, ctf);
  k_fft3<<<B_ * 16, 256, 0, stream>>>(Fc, out);
}